// Round 9
// baseline (87.846 us; speedup 1.0000x reference)
//
#include <hip/hip_runtime.h>

typedef __attribute__((ext_vector_type(8))) short bf16x8;
typedef __attribute__((ext_vector_type(4))) float f32x4;

__device__ __forceinline__ ushort f32_to_bf16(float f) {
    union { float f; unsigned u; } v; v.f = f;
    unsigned b = v.u + 0x7FFF + ((v.u >> 16) & 1);
    return (ushort)(b >> 16);
}
__device__ __forceinline__ float bf16_to_f32(ushort h) {
    union { unsigned u; float f; } v; v.u = ((unsigned)h) << 16;
    return v.f;
}
__device__ __forceinline__ void split2(float x, ushort& a, ushort& b) {
    a = f32_to_bf16(x); float r1 = x - bf16_to_f32(a);
    b = f32_to_bf16(r1);
}

__device__ __forceinline__ void vmwait8() { asm volatile("s_waitcnt vmcnt(8)" ::: "memory"); }
__device__ __forceinline__ void vmwait0() { asm volatile("s_waitcnt vmcnt(0)" ::: "memory"); }
__device__ __forceinline__ void lgwait0() { asm volatile("s_waitcnt lgkmcnt(0)" ::: "memory"); }
__device__ __forceinline__ void blockbar() {
    __builtin_amdgcn_sched_barrier(0);
    __builtin_amdgcn_s_barrier();
    __builtin_amdgcn_sched_barrier(0);
}

// ---- 64 rows x 128B tile (128B rows), for ep staging ----
__device__ __forceinline__ void stage64x64(const ushort* gsrc, int row_stride_elems,
                                           char* lds, int t256) {
    const char* gb = (const char*)gsrc;
    const int rs = row_stride_elems * 2;
#pragma unroll
    for (int j = 0; j < 2; ++j) {
        int o = (j * 256 + t256) * 16;
        int row = o >> 7;
        int col = (o & 127) ^ ((row & 7) << 4);
        __builtin_amdgcn_global_load_lds(
            (const __attribute__((address_space(1))) unsigned int*)(gb + row * rs + col),
            (__attribute__((address_space(3))) unsigned int*)(lds + o), 16, 0, 0);
    }
}
__device__ __forceinline__ bf16x8 fragld(const char* lds, int row, int kbyte) {
    return *(const bf16x8*)(lds + (row << 7) + (kbyte ^ ((row & 7) << 4)));
}

// ---- 64 rows x 256B tile (K=128 elems), row stride 2048 elems, 256 threads ----
__device__ __forceinline__ void stage64x128(const ushort* gsrc, char* lds, int t) {
    const char* gb = (const char*)gsrc;
#pragma unroll
    for (int j = 0; j < 4; ++j) {
        int o = (j * 256 + t) * 16;
        int row = o >> 8;
        int col = (o & 255) ^ ((row & 7) << 4);
        __builtin_amdgcn_global_load_lds(
            (const __attribute__((address_space(1))) unsigned int*)(gb + row * 4096 + col),
            (__attribute__((address_space(3))) unsigned int*)(lds + o), 16, 0, 0);
    }
}
__device__ __forceinline__ bf16x8 fragld256(const char* lds, int row, int kbyte) {
    return *(const bf16x8*)(lds + (row << 8) + (kbyte ^ ((row & 7) << 4)));
}

// =================== prep_all (unchanged from R8) ===================
__global__ __launch_bounds__(256) void prep_all(const float* __restrict__ X,
        ushort* __restrict__ XT1, ushort* __restrict__ XT2,
        ushort* __restrict__ X1o, ushort* __restrict__ X2o,
        const float* __restrict__ Ws, ushort* __restrict__ Ws16,
        const float* __restrict__ Wa, ushort* __restrict__ Wa1,
        const float* __restrict__ Ths, ushort* __restrict__ ThsT) {
    __shared__ float tile[64][68];
    const int bx = blockIdx.x;
    const int t = threadIdx.x;
    if (bx < 256) {
        const int b = bx >> 5, n0 = (bx & 31) * 64;
#pragma unroll
        for (int it = 0; it < 4; ++it) {
            int f = it * 256 + t, r = f >> 4, q = (f & 15) * 4;
            float4 v = *(const float4*)&X[((size_t)b * 2048 + n0 + r) * 64 + q];
            tile[r][q + 0] = v.x; tile[r][q + 1] = v.y; tile[r][q + 2] = v.z; tile[r][q + 3] = v.w;
        }
        __syncthreads();
#pragma unroll
        for (int it = 0; it < 4; ++it) {
            int f = it * 256 + t, c = f >> 4, q = (f & 15) * 4;
            ushort4 h1, h2;
            split2(tile[q + 0][c], h1.x, h2.x); split2(tile[q + 1][c], h1.y, h2.y);
            split2(tile[q + 2][c], h1.z, h2.z); split2(tile[q + 3][c], h1.w, h2.w);
            size_t a = (size_t)(b * 64 + c) * 2048 + n0 + q;
            *(ushort4*)&XT1[a] = h1; *(ushort4*)&XT2[a] = h2;
        }
#pragma unroll
        for (int it = 0; it < 4; ++it) {
            int f = it * 256 + t, n = f >> 4, q = (f & 15) * 4;
            ushort4 h1, h2;
            split2(tile[n][q + 0], h1.x, h2.x); split2(tile[n][q + 1], h1.y, h2.y);
            split2(tile[n][q + 2], h1.z, h2.z); split2(tile[n][q + 3], h1.w, h2.w);
            size_t a = (size_t)(n0 + n) * 512 + b * 64 + q;
            *(ushort4*)&X1o[a] = h1; *(ushort4*)&X2o[a] = h2;
        }
    } else if (bx < 2304) {
        size_t idx = ((size_t)(bx - 256) * 256 + t) * 8;
#pragma unroll
        for (int h = 0; h < 2; ++h) {
            float4 v = *(const float4*)&Ws[idx + h * 4];
            ushort4 a;
            a.x = f32_to_bf16(v.x); a.y = f32_to_bf16(v.y);
            a.z = f32_to_bf16(v.z); a.w = f32_to_bf16(v.w);
            *(ushort4*)&Ws16[idx + h * 4] = a;
        }
    } else if (bx < 4352) {
        size_t idx = ((size_t)(bx - 2304) * 256 + t) * 8;
#pragma unroll
        for (int h = 0; h < 2; ++h) {
            float4 v = *(const float4*)&Wa[idx + h * 4];
            ushort4 a;
            a.x = f32_to_bf16(v.x); a.y = f32_to_bf16(v.y);
            a.z = f32_to_bf16(v.z); a.w = f32_to_bf16(v.w);
            *(ushort4*)&Wa1[idx + h * 4] = a;
        }
    } else {
        int idx = (bx - 4352) * 256 + t;
        int k = idx >> 12, o = (idx >> 6) & 63, i = idx & 63;
        ThsT[idx] = f32_to_bf16(Ths[k * 4096 + i * 64 + o]);
    }
}

// =================== gemm_s v2: 256 thr, 4 waves x 4x4 frags, K-split-4, dbuf ===================
template <int MODE>
__device__ __forceinline__ void gemm_sv2(int bx, const ushort* __restrict__ A,
        const ushort* __restrict__ BT, const ushort* __restrict__ CinT,
        ushort* __restrict__ YT, ushort* __restrict__ Yo, char* ls) {
    const int t = threadIdx.x;
    const int m0 = (bx & 31) * 64, c0 = (bx >> 5) * 64;
    const int w = t >> 6, lane = t & 63, l15 = lane & 15, l4 = lane >> 4;
    const int kb = w * 64 + l4 * 16;          // wave's 32-elem K-slice of the 128-step
    const ushort* Ap = A + (size_t)m0 * 2048;
    const ushort* Bp = BT + (size_t)c0 * 2048;

    f32x4 z = {0.f, 0.f, 0.f, 0.f};
    f32x4 acc[4][4];
#pragma unroll
    for (int i = 0; i < 4; ++i)
#pragma unroll
        for (int j = 0; j < 4; ++j) acc[i][j] = z;

    stage64x128(Ap, ls, t);
    stage64x128(Bp, ls + 16384, t);
    for (int ts = 0; ts < 16; ++ts) {
        char* cur = ls + (ts & 1) * 32768;
        if (ts < 15) {
            char* nxt = ls + ((ts + 1) & 1) * 32768;
            stage64x128(Ap + (ts + 1) * 128, nxt, t);
            stage64x128(Bp + (ts + 1) * 128, nxt + 16384, t);
            vmwait8();                        // my 8 loads for cur are done
        } else {
            vmwait0();
        }
        blockbar();
        bf16x8 aF[4], bF[4];
#pragma unroll
        for (int i = 0; i < 4; ++i) aF[i] = fragld256(cur, i * 16 + l15, kb);
#pragma unroll
        for (int j = 0; j < 4; ++j) bF[j] = fragld256(cur + 16384, j * 16 + l15, kb);
#pragma unroll
        for (int i = 0; i < 4; ++i)
#pragma unroll
            for (int j = 0; j < 4; ++j)
                acc[i][j] = __builtin_amdgcn_mfma_f32_16x16x32_bf16(aF[i], bF[j], acc[i][j], 0, 0, 0);
        lgwait0();
        blockbar();
    }

    // 4-way wave K-reduce: waves 0-2 dump to LDS (3 x [64][65] f32), wave 3 combines
    float* red = (float*)ls;                  // 49920 B
    ushort* tileo = (ushort*)(ls + 50176);    // 8 KB bounce
    if (w < 3) {
#pragma unroll
        for (int i = 0; i < 4; ++i)
#pragma unroll
            for (int j = 0; j < 4; ++j) {
                const int row = i * 16 + l4 * 4;
                const int col = j * 16 + l15;
#pragma unroll
                for (int r = 0; r < 4; ++r) red[w * 4160 + (row + r) * 65 + col] = acc[i][j][r];
            }
    }
    __syncthreads();
    if (w == 3) {
#pragma unroll
        for (int i = 0; i < 4; ++i)
#pragma unroll
            for (int j = 0; j < 4; ++j) {
                const int row = i * 16 + l4 * 4;
                const int col = j * 16 + l15;
                float vv[4];
#pragma unroll
                for (int r = 0; r < 4; ++r) {
                    const int rr = (row + r) * 65 + col;
                    vv[r] = acc[i][j][r] + red[rr] + red[4160 + rr] + red[8320 + rr];
                }
                if (MODE == 1) {
                    ushort4 ci = *(const ushort4*)&CinT[(size_t)(c0 + col) * 2048 + m0 + row];
                    vv[0] = 2.f * vv[0] - bf16_to_f32(ci.x);
                    vv[1] = 2.f * vv[1] - bf16_to_f32(ci.y);
                    vv[2] = 2.f * vv[2] - bf16_to_f32(ci.z);
                    vv[3] = 2.f * vv[3] - bf16_to_f32(ci.w);
                }
                ushort4 p;
                p.x = f32_to_bf16(vv[0]); p.y = f32_to_bf16(vv[1]);
                p.z = f32_to_bf16(vv[2]); p.w = f32_to_bf16(vv[3]);
                *(ushort4*)&YT[(size_t)(c0 + col) * 2048 + m0 + row] = p;
                tileo[(row + 0) * 64 + col] = p.x;
                tileo[(row + 1) * 64 + col] = p.y;
                tileo[(row + 2) * 64 + col] = p.z;
                tileo[(row + 3) * 64 + col] = p.w;
            }
    }
    __syncthreads();
#pragma unroll
    for (int it = 0; it < 2; ++it) {
        int f = it * 256 + t;
        int row = f >> 3, ch = f & 7;
        *(uint4*)&Yo[(size_t)(m0 + row) * 512 + c0 + ch * 8] = *(uint4*)&tileo[row * 64 + ch * 8];
    }
}

// =================== gemm3 v2: 256 thr, 4 waves x 4x4 frags, 2 products, K-split-4 ===================
__device__ __forceinline__ void gemm3v2(int bx, const ushort* __restrict__ A1,
        const ushort* __restrict__ B1, const ushort* __restrict__ B2,
        float* __restrict__ WaXT, char* ls) {
    const int t = threadIdx.x;
    const int m0 = (bx & 31) * 64, c0 = (bx >> 5) * 64;
    const int w = t >> 6, lane = t & 63, l15 = lane & 15, l4 = lane >> 4;
    const int kb = w * 64 + l4 * 16;

    f32x4 z = {0.f, 0.f, 0.f, 0.f};
    f32x4 acc[4][4];
#pragma unroll
    for (int i = 0; i < 4; ++i)
#pragma unroll
        for (int j = 0; j < 4; ++j) acc[i][j] = z;

    for (int k0 = 0; k0 < 2048; k0 += 128) {
        stage64x128(A1 + (size_t)m0 * 2048 + k0, ls, t);
        stage64x128(B1 + (size_t)c0 * 2048 + k0, ls + 16384, t);
        stage64x128(B2 + (size_t)c0 * 2048 + k0, ls + 32768, t);
        __syncthreads();
        bf16x8 aF[4], b1F[4], b2F[4];
#pragma unroll
        for (int i = 0; i < 4; ++i) {
            aF[i]  = fragld256(ls, i * 16 + l15, kb);
            b1F[i] = fragld256(ls + 16384, i * 16 + l15, kb);
            b2F[i] = fragld256(ls + 32768, i * 16 + l15, kb);
        }
#pragma unroll
        for (int i = 0; i < 4; ++i)
#pragma unroll
            for (int j = 0; j < 4; ++j) {
                f32x4 a = acc[i][j];
                a = __builtin_amdgcn_mfma_f32_16x16x32_bf16(aF[i], b1F[j], a, 0, 0, 0);
                a = __builtin_amdgcn_mfma_f32_16x16x32_bf16(aF[i], b2F[j], a, 0, 0, 0);
                acc[i][j] = a;
            }
        __syncthreads();
    }

    float* red = (float*)ls;
    if (w < 3) {
#pragma unroll
        for (int i = 0; i < 4; ++i)
#pragma unroll
            for (int j = 0; j < 4; ++j) {
                const int row = i * 16 + l4 * 4;
                const int col = j * 16 + l15;
#pragma unroll
                for (int r = 0; r < 4; ++r) red[w * 4160 + (row + r) * 65 + col] = acc[i][j][r];
            }
    }
    __syncthreads();
    if (w == 3) {
#pragma unroll
        for (int i = 0; i < 4; ++i)
#pragma unroll
            for (int j = 0; j < 4; ++j) {
                const int row = i * 16 + l4 * 4;
                const int col = j * 16 + l15;
                f32x4 v;
#pragma unroll
                for (int r = 0; r < 4; ++r) {
                    const int rr = (row + r) * 65 + col;
                    v[r] = acc[i][j][r] + red[rr] + red[4160 + rr] + red[8320 + rr];
                }
                *(f32x4*)&WaXT[(size_t)(c0 + col) * 2048 + m0 + row] = v;
            }
    }
}

// =================== gram v2: 256 thr, 256 blocks (8 b x 32 chunks of 64 n) ===================
__device__ __forceinline__ void gramv2(int bx, const float* __restrict__ WaXT,
        const ushort* __restrict__ XT1, const ushort* __restrict__ XT2,
        float* __restrict__ Gpart, char* lsraw) {
    const int b = bx & 7, chunk = bx >> 3;
    float (*Lw)[68] = (float(*)[68])lsraw;
    float (*Rx)[68] = (float(*)[68])(lsraw + 17408);
    const int t = threadIdx.x;
    const int n0 = chunk * 64;
    {
        const int r = t >> 2, q = (t & 3) * 16;
        size_t a = (size_t)(b * 64 + r) * 2048 + n0 + q;
#pragma unroll
        for (int h = 0; h < 4; ++h) {
            *(float4*)&Lw[r][q + h * 4] = *(const float4*)&WaXT[a + h * 4];
            ushort4 h1 = *(const ushort4*)&XT1[a + h * 4];
            ushort4 h2 = *(const ushort4*)&XT2[a + h * 4];
            Rx[r][q + h * 4 + 0] = bf16_to_f32(h1.x) + bf16_to_f32(h2.x);
            Rx[r][q + h * 4 + 1] = bf16_to_f32(h1.y) + bf16_to_f32(h2.y);
            Rx[r][q + h * 4 + 2] = bf16_to_f32(h1.z) + bf16_to_f32(h2.z);
            Rx[r][q + h * 4 + 3] = bf16_to_f32(h1.w) + bf16_to_f32(h2.w);
        }
    }
    __syncthreads();
    {
        const int tx = t & 15, ty = t >> 4;
        float acc[4][4] = {{0.f,0.f,0.f,0.f},{0.f,0.f,0.f,0.f},{0.f,0.f,0.f,0.f},{0.f,0.f,0.f,0.f}};
        for (int n = 0; n < 64; ++n) {
            float a[4], bb[4];
#pragma unroll
            for (int i = 0; i < 4; ++i) { a[i] = Lw[ty * 4 + i][n]; bb[i] = Rx[tx * 4 + i][n]; }
#pragma unroll
            for (int i = 0; i < 4; ++i)
#pragma unroll
                for (int j = 0; j < 4; ++j) acc[i][j] = fmaf(a[i], bb[j], acc[i][j]);
        }
        float* gp = Gpart + (size_t)(chunk * 8 + b) * 4096;
#pragma unroll
        for (int i = 0; i < 4; ++i)
            *(float4*)&gp[(ty * 4 + i) * 64 + tx * 4] =
                make_float4(acc[i][0], acc[i][1], acc[i][2], acc[i][3]);
    }
}

// =================== cheb v2: 256 thr, per-batch 64x64 Chebyshev ===================
__device__ __forceinline__ void chebv2(int b, const float* __restrict__ Gpart,
        const float* __restrict__ Thd, ushort* __restrict__ DT1, ushort* __restrict__ DT2,
        char* lsraw) {
    float (*Gs)[68]  = (float(*)[68])lsraw;
    float (*C2s)[68] = (float(*)[68])(lsraw + 17408);
    float (*C3s)[68] = (float(*)[68])(lsraw + 34816);
    const int t = threadIdx.x;
    for (int i = t; i < 4096; i += 256) {
        float s = 0.f;
#pragma unroll
        for (int c = 0; c < 32; ++c) s += Gpart[((size_t)c * 8 + b) * 4096 + i];
        Gs[i >> 6][i & 63] = s;
    }
    __syncthreads();
    const int tx = t & 15, ty = t >> 4;
    const int r0 = ty * 4, c0 = tx * 4;

    {
        float p[4][4] = {{0,0,0,0},{0,0,0,0},{0,0,0,0},{0,0,0,0}};
        for (int k = 0; k < 64; ++k) {
            float ar[4] = {Gs[r0][k], Gs[r0+1][k], Gs[r0+2][k], Gs[r0+3][k]};
            float4 bv = *(const float4*)&Gs[k][c0];
            float br[4] = {bv.x, bv.y, bv.z, bv.w};
#pragma unroll
            for (int i = 0; i < 4; ++i)
#pragma unroll
                for (int j = 0; j < 4; ++j) p[i][j] = fmaf(ar[i], br[j], p[i][j]);
        }
#pragma unroll
        for (int i = 0; i < 4; ++i)
#pragma unroll
            for (int j = 0; j < 4; ++j)
                C2s[r0+i][c0+j] = 2.f * p[i][j] - ((r0+i) == (c0+j) ? 1.f : 0.f);
    }
    __syncthreads();
    {
        float q[4][4] = {{0,0,0,0},{0,0,0,0},{0,0,0,0},{0,0,0,0}};
        for (int k = 0; k < 64; ++k) {
            float ar[4] = {Gs[r0][k], Gs[r0+1][k], Gs[r0+2][k], Gs[r0+3][k]};
            float4 bv = *(const float4*)&C2s[k][c0];
            float br[4] = {bv.x, bv.y, bv.z, bv.w};
#pragma unroll
            for (int i = 0; i < 4; ++i)
#pragma unroll
                for (int j = 0; j < 4; ++j) q[i][j] = fmaf(ar[i], br[j], q[i][j]);
        }
#pragma unroll
        for (int i = 0; i < 4; ++i)
#pragma unroll
            for (int j = 0; j < 4; ++j)
                C3s[r0+i][c0+j] = 2.f * q[i][j] - Gs[r0+i][c0+j];
    }
    __syncthreads();
    float d[4][4];
    {
#pragma unroll
        for (int i = 0; i < 4; ++i) {
            float4 t0 = *(const float4*)&Thd[(r0+i) * 64 + c0];
            d[i][0] = t0.x; d[i][1] = t0.y; d[i][2] = t0.z; d[i][3] = t0.w;
        }
        for (int k = 0; k < 64; ++k) {
            float4 t1 = *(const float4*)&Thd[4096 + k * 64 + c0];
            float4 t2 = *(const float4*)&Thd[8192 + k * 64 + c0];
            float4 t3 = *(const float4*)&Thd[12288 + k * 64 + c0];
            float a1[4] = {Gs[r0][k], Gs[r0+1][k], Gs[r0+2][k], Gs[r0+3][k]};
            float a2[4] = {C2s[r0][k], C2s[r0+1][k], C2s[r0+2][k], C2s[r0+3][k]};
            float a3[4] = {C3s[r0][k], C3s[r0+1][k], C3s[r0+2][k], C3s[r0+3][k]};
            float b1[4] = {t1.x, t1.y, t1.z, t1.w};
            float b2[4] = {t2.x, t2.y, t2.z, t2.w};
            float b3[4] = {t3.x, t3.y, t3.z, t3.w};
#pragma unroll
            for (int i = 0; i < 4; ++i)
#pragma unroll
                for (int j = 0; j < 4; ++j) {
                    d[i][j] = fmaf(a1[i], b1[j], d[i][j]);
                    d[i][j] = fmaf(a2[i], b2[j], d[i][j]);
                    d[i][j] = fmaf(a3[i], b3[j], d[i][j]);
                }
        }
    }
    __syncthreads();
#pragma unroll
    for (int i = 0; i < 4; ++i)
#pragma unroll
        for (int j = 0; j < 4; ++j) Gs[r0 + i][c0 + j] = d[i][j];
    __syncthreads();
#pragma unroll
    for (int it = 0; it < 16; ++it) {
        int idx = it * 256 + t;              // o*64 + i (transposed emit)
        int o = idx >> 6, ii = idx & 63;
        ushort h1, h2;
        split2(Gs[ii][o], h1, h2);
        DT1[b * 4096 + idx] = h1;
        DT2[b * 4096 + idx] = h2;
    }
}

// =================== mega kernels (all 256-thread blocks, 64KB LDS, 2 blk/CU) ===================
__global__ __launch_bounds__(256, 2) void mega1(const ushort* __restrict__ Wa1,
        const ushort* __restrict__ XT1, const ushort* __restrict__ XT2,
        float* __restrict__ WaXT,
        const ushort* __restrict__ Ws16, ushort* __restrict__ Y1T, ushort* __restrict__ Y1o) {
    __shared__ __align__(16) char ls[65536];
    const int bx = blockIdx.x;
    if (bx < 256) gemm3v2(bx, Wa1, XT1, XT2, WaXT, ls);
    else          gemm_sv2<0>(bx - 256, Ws16, XT1, nullptr, Y1T, Y1o, ls);
}

__global__ __launch_bounds__(256, 2) void mega2(const ushort* __restrict__ Ws16,
        const ushort* __restrict__ Y1T, const ushort* __restrict__ XT1,
        ushort* __restrict__ Y2T, ushort* __restrict__ Y2o,
        const float* __restrict__ WaXT, const ushort* __restrict__ XT2,
        float* __restrict__ Gpart) {
    __shared__ __align__(16) char ls[65536];
    const int bx = blockIdx.x;
    if (bx < 256) gemm_sv2<1>(bx, Ws16, Y1T, XT1, Y2T, Y2o, ls);
    else          gramv2(bx - 256, WaXT, XT1, XT2, Gpart, ls);
}

__global__ __launch_bounds__(256, 2) void mega3(const ushort* __restrict__ Ws16,
        const ushort* __restrict__ Y2T, const ushort* __restrict__ Y1T,
        ushort* __restrict__ Y3T, ushort* __restrict__ Y3o,
        const float* __restrict__ Gpart, const float* __restrict__ Thd,
        ushort* __restrict__ DT1, ushort* __restrict__ DT2) {
    __shared__ __align__(16) char ls[65536];
    const int bx = blockIdx.x;
    if (bx < 256) gemm_sv2<1>(bx, Ws16, Y2T, Y1T, Y3T, Y3o, ls);
    else          chebv2(bx - 256, Gpart, Thd, DT1, DT2, ls);
}

// =================== fused epilogue (unchanged from R8) ===================
__global__ __launch_bounds__(256) void ep_fused(const ushort* __restrict__ ThsT,
                                                const ushort* __restrict__ DT1, const ushort* __restrict__ DT2,
                                                const ushort* __restrict__ X1o, const ushort* __restrict__ X2o,
                                                const ushort* __restrict__ Y1o, const ushort* __restrict__ Y2o,
                                                const ushort* __restrict__ Y3o,
                                                float* __restrict__ out) {
    __shared__ __align__(16) char ls[65536];
    const int b = blockIdx.y, n0 = blockIdx.x * 64;
    const int t = threadIdx.x, lane = t & 63, w = t >> 6, wr = w >> 1, wc = w & 1;
    const int l15 = lane & 15, l4 = lane >> 4;
    stage64x64(X1o + (size_t)n0 * 512 + b * 64, 512, ls + 0 * 8192, t);
    stage64x64(Y1o + (size_t)n0 * 512 + b * 64, 512, ls + 1 * 8192, t);
    stage64x64(Y2o + (size_t)n0 * 512 + b * 64, 512, ls + 2 * 8192, t);
    stage64x64(Y3o + (size_t)n0 * 512 + b * 64, 512, ls + 3 * 8192, t);
    stage64x64(ThsT + 0 * 4096, 64, ls + 4 * 8192, t);
    stage64x64(ThsT + 1 * 4096, 64, ls + 5 * 8192, t);
    stage64x64(ThsT + 2 * 4096, 64, ls + 6 * 8192, t);
    stage64x64(ThsT + 3 * 4096, 64, ls + 7 * 8192, t);
    __syncthreads();
    f32x4 z = {0.f, 0.f, 0.f, 0.f};
    f32x4 as[2][2], ad[2][2];
    as[0][0] = z; as[0][1] = z; as[1][0] = z; as[1][1] = z;
    ad[0][0] = z; ad[0][1] = z; ad[1][0] = z; ad[1][1] = z;
#pragma unroll
    for (int s = 0; s < 2; ++s) {
        const int kb = s * 64 + l4 * 16;
#pragma unroll
        for (int p = 0; p < 4; ++p) {
            bf16x8 aF[2], bF[2];
#pragma unroll
            for (int f = 0; f < 2; ++f) {
                aF[f] = fragld(ls + (4 + p) * 8192, wr * 32 + f * 16 + l15, kb);
                bF[f] = fragld(ls + p * 8192, wc * 32 + f * 16 + l15, kb);
            }
#pragma unroll
            for (int i = 0; i < 2; ++i)
#pragma unroll
                for (int j = 0; j < 2; ++j)
                    as[i][j] = __builtin_amdgcn_mfma_f32_16x16x32_bf16(aF[i], bF[j], as[i][j], 0, 0, 0);
        }
    }
    __syncthreads();
    stage64x64(DT1 + b * 4096, 64, ls + 1 * 8192, t);
    stage64x64(DT2 + b * 4096, 64, ls + 2 * 8192, t);
    stage64x64(X2o + (size_t)n0 * 512 + b * 64, 512, ls + 3 * 8192, t);
    __syncthreads();
#pragma unroll
    for (int s = 0; s < 2; ++s) {
        const int kb = s * 64 + l4 * 16;
        bf16x8 a1[2], a2[2], b0[2], b3[2];
#pragma unroll
        for (int f = 0; f < 2; ++f) {
            a1[f] = fragld(ls + 1 * 8192, wr * 32 + f * 16 + l15, kb);
            a2[f] = fragld(ls + 2 * 8192, wr * 32 + f * 16 + l15, kb);
            b0[f] = fragld(ls + 0 * 8192, wc * 32 + f * 16 + l15, kb);
            b3[f] = fragld(ls + 3 * 8192, wc * 32 + f * 16 + l15, kb);
        }
#pragma unroll
        for (int i = 0; i < 2; ++i)
#pragma unroll
            for (int j = 0; j < 2; ++j) {
                f32x4 a = ad[i][j];
                a = __builtin_amdgcn_mfma_f32_16x16x32_bf16(a1[i], b0[j], a, 0, 0, 0);
                a = __builtin_amdgcn_mfma_f32_16x16x32_bf16(a1[i], b3[j], a, 0, 0, 0);
                a = __builtin_amdgcn_mfma_f32_16x16x32_bf16(a2[i], b0[j], a, 0, 0, 0);
                ad[i][j] = a;
            }
    }
#pragma unroll
    for (int i = 0; i < 2; ++i)
#pragma unroll
        for (int j = 0; j < 2; ++j) {
            const int ob = wr * 32 + i * 16 + l4 * 4;
            const int nn = wc * 32 + j * 16 + l15;
            float4 o4;
            o4.x = fmaxf(as[i][j][0], 0.f) + fmaxf(ad[i][j][0], 0.f);
            o4.y = fmaxf(as[i][j][1], 0.f) + fmaxf(ad[i][j][1], 0.f);
            o4.z = fmaxf(as[i][j][2], 0.f) + fmaxf(ad[i][j][2], 0.f);
            o4.w = fmaxf(as[i][j][3], 0.f) + fmaxf(ad[i][j][3], 0.f);
            *(float4*)&out[((size_t)b * 2048 + n0 + nn) * 64 + ob] = o4;
        }
}

extern "C" void kernel_launch(void* const* d_in, const int* in_sizes, int n_in,
                              void* d_out, int out_size, void* d_ws, size_t ws_size,
                              hipStream_t stream) {
    (void)in_sizes; (void)n_in; (void)out_size;
    const float* X   = (const float*)d_in[0];
    const float* Ws  = (const float*)d_in[1];
    const float* Wa  = (const float*)d_in[2];
    const float* Ths = (const float*)d_in[3];
    const float* Thd = (const float*)d_in[4];

    char* p = (char*)d_ws;
    auto alloc = [&](size_t bytes) { char* r = p; p += (bytes + 255) & ~(size_t)255; return r; };
    ushort* XT1 = (ushort*)alloc(512ull * 2048 * 2);
    ushort* XT2 = (ushort*)alloc(512ull * 2048 * 2);
    ushort* X1o = (ushort*)alloc(2048ull * 512 * 2);
    ushort* X2o = (ushort*)alloc(2048ull * 512 * 2);
    ushort* Ws16 = (ushort*)alloc(2048ull * 2048 * 2);
    ushort* Wa1 = (ushort*)alloc(2048ull * 2048 * 2);
    ushort* Y1T = (ushort*)alloc(512ull * 2048 * 2);
    ushort* Y2T = (ushort*)alloc(512ull * 2048 * 2);
    ushort* Y3T = (ushort*)alloc(512ull * 2048 * 2);
    ushort* Y1o = (ushort*)alloc(2048ull * 512 * 2);
    ushort* Y2o = (ushort*)alloc(2048ull * 512 * 2);
    ushort* Y3o = (ushort*)alloc(2048ull * 512 * 2);
    float*  Gpart = (float*)alloc(32ull * 8 * 4096 * 4);
    ushort* DT1 = (ushort*)alloc(8ull * 4096 * 2);
    ushort* DT2 = (ushort*)alloc(8ull * 4096 * 2);
    ushort* ThsT = (ushort*)alloc(4ull * 4096 * 2);
    if ((size_t)(p - (char*)d_ws) > ws_size) return;   // visible failure if ws too small
    float* WaXT = (float*)d_out;                       // 4MB scratch, overwritten by ep_fused later

    prep_all<<<4416, 256, 0, stream>>>(X, XT1, XT2, X1o, X2o, Ws, Ws16, Wa, Wa1, Ths, ThsT);
    mega1<<<512, 256, 0, stream>>>(Wa1, XT1, XT2, WaXT, Ws16, Y1T, Y1o);
    mega2<<<512, 256, 0, stream>>>(Ws16, Y1T, XT1, Y2T, Y2o, WaXT, XT2, Gpart);
    mega3<<<264, 256, 0, stream>>>(Ws16, Y2T, Y1T, Y3T, Y3o, Gpart, Thd, DT1, DT2);
    ep_fused<<<dim3(32, 8), 256, 0, stream>>>(ThsT, DT1, DT2, X1o, X2o, Y1o, Y2o, Y3o, (float*)d_out);
}

// Round 10
// 86.803 us; speedup vs baseline: 1.0120x; 1.0120x over previous
//
#include <hip/hip_runtime.h>

typedef __attribute__((ext_vector_type(8))) short bf16x8;
typedef __attribute__((ext_vector_type(4))) float f32x4;

__device__ __forceinline__ ushort f32_to_bf16(float f) {
    union { float f; unsigned u; } v; v.f = f;
    unsigned b = v.u + 0x7FFF + ((v.u >> 16) & 1);
    return (ushort)(b >> 16);
}
__device__ __forceinline__ float bf16_to_f32(ushort h) {
    union { unsigned u; float f; } v; v.u = ((unsigned)h) << 16;
    return v.f;
}
__device__ __forceinline__ void split2(float x, ushort& a, ushort& b) {
    a = f32_to_bf16(x); float r1 = x - bf16_to_f32(a);
    b = f32_to_bf16(r1);
}

__device__ __forceinline__ void vmwait4() { asm volatile("s_waitcnt vmcnt(4)" ::: "memory"); }
__device__ __forceinline__ void vmwait0() { asm volatile("s_waitcnt vmcnt(0)" ::: "memory"); }
__device__ __forceinline__ void lgwait0() { asm volatile("s_waitcnt lgkmcnt(0)" ::: "memory"); }
__device__ __forceinline__ void blockbar() {
    __builtin_amdgcn_sched_barrier(0);
    __builtin_amdgcn_s_barrier();
    __builtin_amdgcn_sched_barrier(0);
}

// ---- 64 rows x 128B tile (128B rows) for ep staging, 256 threads x 2 ----
__device__ __forceinline__ void stage64x64(const ushort* gsrc, int row_stride_elems,
                                           char* lds, int t256) {
    const char* gb = (const char*)gsrc;
    const int rs = row_stride_elems * 2;
#pragma unroll
    for (int j = 0; j < 2; ++j) {
        int o = (j * 256 + t256) * 16;
        int row = o >> 7;
        int col = (o & 127) ^ ((row & 7) << 4);
        __builtin_amdgcn_global_load_lds(
            (const __attribute__((address_space(1))) unsigned int*)(gb + row * rs + col),
            (__attribute__((address_space(3))) unsigned int*)(lds + o), 16, 0, 0);
    }
}
__device__ __forceinline__ bf16x8 fragld(const char* lds, int row, int kbyte) {
    return *(const bf16x8*)(lds + (row << 7) + (kbyte ^ ((row & 7) << 4)));
}

// ---- 64 rows x 256B tile (K=128 elems), row stride 2048 elems, 512 threads x 2 ----
__device__ __forceinline__ void stage64x128_512(const ushort* gsrc, char* lds, int t) {
    const char* gb = (const char*)gsrc;
#pragma unroll
    for (int j = 0; j < 2; ++j) {
        int o = (j * 512 + t) * 16;
        int row = o >> 8;
        int col = (o & 255) ^ ((row & 7) << 4);
        __builtin_amdgcn_global_load_lds(
            (const __attribute__((address_space(1))) unsigned int*)(gb + row * 4096 + col),
            (__attribute__((address_space(3))) unsigned int*)(lds + o), 16, 0, 0);
    }
}
__device__ __forceinline__ bf16x8 fragld256(const char* lds, int row, int kbyte) {
    return *(const bf16x8*)(lds + (row << 8) + (kbyte ^ ((row & 7) << 4)));
}

// =================== prep_all (unchanged from R8) ===================
__global__ __launch_bounds__(256) void prep_all(const float* __restrict__ X,
        ushort* __restrict__ XT1, ushort* __restrict__ XT2,
        ushort* __restrict__ X1o, ushort* __restrict__ X2o,
        const float* __restrict__ Ws, ushort* __restrict__ Ws16,
        const float* __restrict__ Wa, ushort* __restrict__ Wa1,
        const float* __restrict__ Ths, ushort* __restrict__ ThsT) {
    __shared__ float tile[64][68];
    const int bx = blockIdx.x;
    const int t = threadIdx.x;
    if (bx < 256) {
        const int b = bx >> 5, n0 = (bx & 31) * 64;
#pragma unroll
        for (int it = 0; it < 4; ++it) {
            int f = it * 256 + t, r = f >> 4, q = (f & 15) * 4;
            float4 v = *(const float4*)&X[((size_t)b * 2048 + n0 + r) * 64 + q];
            tile[r][q + 0] = v.x; tile[r][q + 1] = v.y; tile[r][q + 2] = v.z; tile[r][q + 3] = v.w;
        }
        __syncthreads();
#pragma unroll
        for (int it = 0; it < 4; ++it) {
            int f = it * 256 + t, c = f >> 4, q = (f & 15) * 4;
            ushort4 h1, h2;
            split2(tile[q + 0][c], h1.x, h2.x); split2(tile[q + 1][c], h1.y, h2.y);
            split2(tile[q + 2][c], h1.z, h2.z); split2(tile[q + 3][c], h1.w, h2.w);
            size_t a = (size_t)(b * 64 + c) * 2048 + n0 + q;
            *(ushort4*)&XT1[a] = h1; *(ushort4*)&XT2[a] = h2;
        }
#pragma unroll
        for (int it = 0; it < 4; ++it) {
            int f = it * 256 + t, n = f >> 4, q = (f & 15) * 4;
            ushort4 h1, h2;
            split2(tile[n][q + 0], h1.x, h2.x); split2(tile[n][q + 1], h1.y, h2.y);
            split2(tile[n][q + 2], h1.z, h2.z); split2(tile[n][q + 3], h1.w, h2.w);
            size_t a = (size_t)(n0 + n) * 512 + b * 64 + q;
            *(ushort4*)&X1o[a] = h1; *(ushort4*)&X2o[a] = h2;
        }
    } else if (bx < 2304) {
        size_t idx = ((size_t)(bx - 256) * 256 + t) * 8;
#pragma unroll
        for (int h = 0; h < 2; ++h) {
            float4 v = *(const float4*)&Ws[idx + h * 4];
            ushort4 a;
            a.x = f32_to_bf16(v.x); a.y = f32_to_bf16(v.y);
            a.z = f32_to_bf16(v.z); a.w = f32_to_bf16(v.w);
            *(ushort4*)&Ws16[idx + h * 4] = a;
        }
    } else if (bx < 4352) {
        size_t idx = ((size_t)(bx - 2304) * 256 + t) * 8;
#pragma unroll
        for (int h = 0; h < 2; ++h) {
            float4 v = *(const float4*)&Wa[idx + h * 4];
            ushort4 a;
            a.x = f32_to_bf16(v.x); a.y = f32_to_bf16(v.y);
            a.z = f32_to_bf16(v.z); a.w = f32_to_bf16(v.w);
            *(ushort4*)&Wa1[idx + h * 4] = a;
        }
    } else {
        int idx = (bx - 4352) * 256 + t;
        int k = idx >> 12, o = (idx >> 6) & 63, i = idx & 63;
        ThsT[idx] = f32_to_bf16(Ths[k * 4096 + i * 64 + o]);
    }
}

// =================== gemm_s v3: 512 thr, 8 waves = K4 x N2, K-step 128, dbuf ===================
template <int MODE>
__device__ __forceinline__ void gemm_sv3(int bx, const ushort* __restrict__ A,
        const ushort* __restrict__ BT, const ushort* __restrict__ CinT,
        ushort* __restrict__ YT, ushort* __restrict__ Yo, char* ls) {
    const int t = threadIdx.x;
    const int m0 = (bx & 31) * 64, c0 = (bx >> 5) * 64;
    const int w = t >> 6, kw = w >> 1, nw = w & 1;
    const int lane = t & 63, l15 = lane & 15, l4 = lane >> 4;
    const int kb = kw * 64 + l4 * 16;       // byte offset inside 256B K-row
    const ushort* Ap = A + (size_t)m0 * 2048;
    const ushort* Bp = BT + (size_t)c0 * 2048;

    f32x4 z = {0.f, 0.f, 0.f, 0.f};
    f32x4 acc[4][2];
#pragma unroll
    for (int i = 0; i < 4; ++i) { acc[i][0] = z; acc[i][1] = z; }

    stage64x128_512(Ap, ls, t);
    stage64x128_512(Bp, ls + 16384, t);
    for (int ts = 0; ts < 16; ++ts) {
        char* cur = ls + (ts & 1) * 32768;
        if (ts < 15) {
            char* nxt = ls + ((ts + 1) & 1) * 32768;
            stage64x128_512(Ap + (ts + 1) * 128, nxt, t);
            stage64x128_512(Bp + (ts + 1) * 128, nxt + 16384, t);
            vmwait4();                      // my 4 loads for cur are done
        } else {
            vmwait0();
        }
        blockbar();
        bf16x8 aF[4], bF[2];
#pragma unroll
        for (int i = 0; i < 4; ++i) aF[i] = fragld256(cur, i * 16 + l15, kb);
#pragma unroll
        for (int j = 0; j < 2; ++j) bF[j] = fragld256(cur + 16384, nw * 32 + j * 16 + l15, kb);
#pragma unroll
        for (int i = 0; i < 4; ++i)
#pragma unroll
            for (int j = 0; j < 2; ++j)
                acc[i][j] = __builtin_amdgcn_mfma_f32_16x16x32_bf16(aF[i], bF[j], acc[i][j], 0, 0, 0);
        lgwait0();
        blockbar();
    }

    // 4-way K-reduce: kw=1..3 dump to LDS (6 regions of 64x32, stride 33), kw=0 combines
    float* red = (float*)ls;                // 6*2112*4 = 50688 B
    ushort* tileo = (ushort*)(ls + 51200);  // 8 KB bounce
    if (kw > 0) {
        float* rg = red + ((kw - 1) * 2 + nw) * 2112;
#pragma unroll
        for (int i = 0; i < 4; ++i)
#pragma unroll
            for (int j = 0; j < 2; ++j) {
                const int row = i * 16 + l4 * 4;
                const int colL = j * 16 + l15;
#pragma unroll
                for (int r = 0; r < 4; ++r) rg[(row + r) * 33 + colL] = acc[i][j][r];
            }
    }
    __syncthreads();
    if (kw == 0) {
#pragma unroll
        for (int i = 0; i < 4; ++i)
#pragma unroll
            for (int j = 0; j < 2; ++j) {
                const int row = i * 16 + l4 * 4;
                const int colL = j * 16 + l15;
                const int col = nw * 32 + colL;
                float vv[4];
#pragma unroll
                for (int r = 0; r < 4; ++r) {
                    const int rr = (row + r) * 33 + colL;
                    vv[r] = acc[i][j][r] + red[nw * 2112 + rr]
                          + red[(2 + nw) * 2112 + rr] + red[(4 + nw) * 2112 + rr];
                }
                if (MODE == 1) {
                    ushort4 ci = *(const ushort4*)&CinT[(size_t)(c0 + col) * 2048 + m0 + row];
                    vv[0] = 2.f * vv[0] - bf16_to_f32(ci.x);
                    vv[1] = 2.f * vv[1] - bf16_to_f32(ci.y);
                    vv[2] = 2.f * vv[2] - bf16_to_f32(ci.z);
                    vv[3] = 2.f * vv[3] - bf16_to_f32(ci.w);
                }
                ushort4 p;
                p.x = f32_to_bf16(vv[0]); p.y = f32_to_bf16(vv[1]);
                p.z = f32_to_bf16(vv[2]); p.w = f32_to_bf16(vv[3]);
                *(ushort4*)&YT[(size_t)(c0 + col) * 2048 + m0 + row] = p;
                tileo[(row + 0) * 64 + col] = p.x;
                tileo[(row + 1) * 64 + col] = p.y;
                tileo[(row + 2) * 64 + col] = p.z;
                tileo[(row + 3) * 64 + col] = p.w;
            }
    }
    __syncthreads();
    {   // 512 threads copy 8KB bounce -> Yo
        int row = t >> 3, ch = t & 7;
        *(uint4*)&Yo[(size_t)(m0 + row) * 512 + c0 + ch * 8] = *(uint4*)&tileo[row * 64 + ch * 8];
    }
}

// =================== gemm3 v3: 512 thr, K4 x N2, K-step 128, 2 products, single-buf ===================
__device__ __forceinline__ void gemm3v3(int bx, const ushort* __restrict__ A1,
        const ushort* __restrict__ B1, const ushort* __restrict__ B2,
        float* __restrict__ WaXT, char* ls) {
    const int t = threadIdx.x;
    const int m0 = (bx & 31) * 64, c0 = (bx >> 5) * 64;
    const int w = t >> 6, kw = w >> 1, nw = w & 1;
    const int lane = t & 63, l15 = lane & 15, l4 = lane >> 4;
    const int kb = kw * 64 + l4 * 16;

    f32x4 z = {0.f, 0.f, 0.f, 0.f};
    f32x4 acc[4][2];
#pragma unroll
    for (int i = 0; i < 4; ++i) { acc[i][0] = z; acc[i][1] = z; }

    for (int k0 = 0; k0 < 2048; k0 += 128) {
        stage64x128_512(A1 + (size_t)m0 * 2048 + k0, ls, t);
        stage64x128_512(B1 + (size_t)c0 * 2048 + k0, ls + 16384, t);
        stage64x128_512(B2 + (size_t)c0 * 2048 + k0, ls + 32768, t);
        __syncthreads();
        bf16x8 aF[4], b1F[2], b2F[2];
#pragma unroll
        for (int i = 0; i < 4; ++i) aF[i] = fragld256(ls, i * 16 + l15, kb);
#pragma unroll
        for (int j = 0; j < 2; ++j) {
            b1F[j] = fragld256(ls + 16384, nw * 32 + j * 16 + l15, kb);
            b2F[j] = fragld256(ls + 32768, nw * 32 + j * 16 + l15, kb);
        }
#pragma unroll
        for (int i = 0; i < 4; ++i)
#pragma unroll
            for (int j = 0; j < 2; ++j) {
                f32x4 a = acc[i][j];
                a = __builtin_amdgcn_mfma_f32_16x16x32_bf16(aF[i], b1F[j], a, 0, 0, 0);
                a = __builtin_amdgcn_mfma_f32_16x16x32_bf16(aF[i], b2F[j], a, 0, 0, 0);
                acc[i][j] = a;
            }
        __syncthreads();
    }

    float* red = (float*)ls;
    if (kw > 0) {
        float* rg = red + ((kw - 1) * 2 + nw) * 2112;
#pragma unroll
        for (int i = 0; i < 4; ++i)
#pragma unroll
            for (int j = 0; j < 2; ++j) {
                const int row = i * 16 + l4 * 4;
                const int colL = j * 16 + l15;
#pragma unroll
                for (int r = 0; r < 4; ++r) rg[(row + r) * 33 + colL] = acc[i][j][r];
            }
    }
    __syncthreads();
    if (kw == 0) {
#pragma unroll
        for (int i = 0; i < 4; ++i)
#pragma unroll
            for (int j = 0; j < 2; ++j) {
                const int row = i * 16 + l4 * 4;
                const int colL = j * 16 + l15;
                const int col = nw * 32 + colL;
                f32x4 v;
#pragma unroll
                for (int r = 0; r < 4; ++r) {
                    const int rr = (row + r) * 33 + colL;
                    v[r] = acc[i][j][r] + red[nw * 2112 + rr]
                         + red[(2 + nw) * 2112 + rr] + red[(4 + nw) * 2112 + rr];
                }
                *(f32x4*)&WaXT[(size_t)(c0 + col) * 2048 + m0 + row] = v;
            }
    }
}

// =================== gram body (R8, 512 thr) ===================
__device__ __forceinline__ void gram_body(int bx, const float* __restrict__ WaXT,
        const ushort* __restrict__ XT1, const ushort* __restrict__ XT2,
        float* __restrict__ Gpart, char* lsraw) {
    const int b = bx & 7, chunk = bx >> 3;
    float (*Lw)[68] = (float(*)[68])lsraw;
    float (*Rx)[68] = (float(*)[68])(lsraw + 64 * 68 * 4);
    const int t = threadIdx.x;
    const int n0 = chunk * 64;
    {
        const int r = t >> 3, q = (t & 7) * 8;
        size_t a = (size_t)(b * 64 + r) * 2048 + n0 + q;
        *(float4*)&Lw[r][q]     = *(const float4*)&WaXT[a];
        *(float4*)&Lw[r][q + 4] = *(const float4*)&WaXT[a + 4];
#pragma unroll
        for (int h = 0; h < 2; ++h) {
            ushort4 h1 = *(const ushort4*)&XT1[a + h * 4];
            ushort4 h2 = *(const ushort4*)&XT2[a + h * 4];
            Rx[r][q + h * 4 + 0] = bf16_to_f32(h1.x) + bf16_to_f32(h2.x);
            Rx[r][q + h * 4 + 1] = bf16_to_f32(h1.y) + bf16_to_f32(h2.y);
            Rx[r][q + h * 4 + 2] = bf16_to_f32(h1.z) + bf16_to_f32(h2.z);
            Rx[r][q + h * 4 + 3] = bf16_to_f32(h1.w) + bf16_to_f32(h2.w);
        }
    }
    __syncthreads();
    if (t < 256) {
        const int tx = t & 15, ty = t >> 4;
        float acc[4][4] = {{0.f,0.f,0.f,0.f},{0.f,0.f,0.f,0.f},{0.f,0.f,0.f,0.f},{0.f,0.f,0.f,0.f}};
        for (int n = 0; n < 64; ++n) {
            float a[4], bb[4];
#pragma unroll
            for (int i = 0; i < 4; ++i) { a[i] = Lw[ty * 4 + i][n]; bb[i] = Rx[tx * 4 + i][n]; }
#pragma unroll
            for (int i = 0; i < 4; ++i)
#pragma unroll
                for (int j = 0; j < 4; ++j) acc[i][j] = fmaf(a[i], bb[j], acc[i][j]);
        }
        float* gp = Gpart + (size_t)(chunk * 8 + b) * 4096;
#pragma unroll
        for (int i = 0; i < 4; ++i)
            *(float4*)&gp[(ty * 4 + i) * 64 + tx * 4] =
                make_float4(acc[i][0], acc[i][1], acc[i][2], acc[i][3]);
    }
}

// =================== cheb body (R8, 512 thr) ===================
__device__ __forceinline__ void cheb_body(int b, const float* __restrict__ Gpart,
        const float* __restrict__ Thd, ushort* __restrict__ DT1, ushort* __restrict__ DT2,
        char* lsraw) {
    float (*Gs)[68]  = (float(*)[68])lsraw;
    float (*C2s)[68] = (float(*)[68])(lsraw + 17408);
    float (*C3s)[68] = (float(*)[68])(lsraw + 34816);
    const int t = threadIdx.x;
    for (int i = t; i < 4096; i += 512) {
        float s = 0.f;
#pragma unroll
        for (int c = 0; c < 32; ++c) s += Gpart[((size_t)c * 8 + b) * 4096 + i];
        Gs[i >> 6][i & 63] = s;
    }
    __syncthreads();
    const int tx = t & 15, ty = (t >> 4) & 15;
    const int r0 = ty * 4, c0 = tx * 4;
    const bool act = t < 256;

    if (act) {
        float p[4][4] = {{0,0,0,0},{0,0,0,0},{0,0,0,0},{0,0,0,0}};
        for (int k = 0; k < 64; ++k) {
            float ar[4] = {Gs[r0][k], Gs[r0+1][k], Gs[r0+2][k], Gs[r0+3][k]};
            float4 bv = *(const float4*)&Gs[k][c0];
            float br[4] = {bv.x, bv.y, bv.z, bv.w};
#pragma unroll
            for (int i = 0; i < 4; ++i)
#pragma unroll
                for (int j = 0; j < 4; ++j) p[i][j] = fmaf(ar[i], br[j], p[i][j]);
        }
#pragma unroll
        for (int i = 0; i < 4; ++i)
#pragma unroll
            for (int j = 0; j < 4; ++j)
                C2s[r0+i][c0+j] = 2.f * p[i][j] - ((r0+i) == (c0+j) ? 1.f : 0.f);
    }
    __syncthreads();
    if (act) {
        float q[4][4] = {{0,0,0,0},{0,0,0,0},{0,0,0,0},{0,0,0,0}};
        for (int k = 0; k < 64; ++k) {
            float ar[4] = {Gs[r0][k], Gs[r0+1][k], Gs[r0+2][k], Gs[r0+3][k]};
            float4 bv = *(const float4*)&C2s[k][c0];
            float br[4] = {bv.x, bv.y, bv.z, bv.w};
#pragma unroll
            for (int i = 0; i < 4; ++i)
#pragma unroll
                for (int j = 0; j < 4; ++j) q[i][j] = fmaf(ar[i], br[j], q[i][j]);
        }
#pragma unroll
        for (int i = 0; i < 4; ++i)
#pragma unroll
            for (int j = 0; j < 4; ++j)
                C3s[r0+i][c0+j] = 2.f * q[i][j] - Gs[r0+i][c0+j];
    }
    __syncthreads();
    float d[4][4];
    if (act) {
#pragma unroll
        for (int i = 0; i < 4; ++i) {
            float4 t0 = *(const float4*)&Thd[(r0+i) * 64 + c0];
            d[i][0] = t0.x; d[i][1] = t0.y; d[i][2] = t0.z; d[i][3] = t0.w;
        }
        for (int k = 0; k < 64; ++k) {
            float4 t1 = *(const float4*)&Thd[4096 + k * 64 + c0];
            float4 t2 = *(const float4*)&Thd[8192 + k * 64 + c0];
            float4 t3 = *(const float4*)&Thd[12288 + k * 64 + c0];
            float a1[4] = {Gs[r0][k], Gs[r0+1][k], Gs[r0+2][k], Gs[r0+3][k]};
            float a2[4] = {C2s[r0][k], C2s[r0+1][k], C2s[r0+2][k], C2s[r0+3][k]};
            float a3[4] = {C3s[r0][k], C3s[r0+1][k], C3s[r0+2][k], C3s[r0+3][k]};
            float b1[4] = {t1.x, t1.y, t1.z, t1.w};
            float b2[4] = {t2.x, t2.y, t2.z, t2.w};
            float b3[4] = {t3.x, t3.y, t3.z, t3.w};
#pragma unroll
            for (int i = 0; i < 4; ++i)
#pragma unroll
                for (int j = 0; j < 4; ++j) {
                    d[i][j] = fmaf(a1[i], b1[j], d[i][j]);
                    d[i][j] = fmaf(a2[i], b2[j], d[i][j]);
                    d[i][j] = fmaf(a3[i], b3[j], d[i][j]);
                }
        }
    }
    __syncthreads();
    if (act) {
#pragma unroll
        for (int i = 0; i < 4; ++i)
#pragma unroll
            for (int j = 0; j < 4; ++j) Gs[r0 + i][c0 + j] = d[i][j];
    }
    __syncthreads();
    for (int it = 0; it < 8; ++it) {
        int idx = it * 512 + t;              // o*64 + i (transposed emit)
        int o = idx >> 6, ii = idx & 63;
        ushort h1, h2;
        split2(Gs[ii][o], h1, h2);
        DT1[b * 4096 + idx] = h1;
        DT2[b * 4096 + idx] = h2;
    }
}

// =================== mega kernels (512 thr, 64KB LDS, 2 blk/CU = 4 waves/SIMD) ===================
__global__ __launch_bounds__(512, 4) void mega1(const ushort* __restrict__ Wa1,
        const ushort* __restrict__ XT1, const ushort* __restrict__ XT2,
        float* __restrict__ WaXT,
        const ushort* __restrict__ Ws16, ushort* __restrict__ Y1T, ushort* __restrict__ Y1o) {
    __shared__ __align__(16) char ls[65536];
    const int bx = blockIdx.x;
    if (bx < 256) gemm3v3(bx, Wa1, XT1, XT2, WaXT, ls);
    else          gemm_sv3<0>(bx - 256, Ws16, XT1, nullptr, Y1T, Y1o, ls);
}

__global__ __launch_bounds__(512, 4) void mega2(const ushort* __restrict__ Ws16,
        const ushort* __restrict__ Y1T, const ushort* __restrict__ XT1,
        ushort* __restrict__ Y2T, ushort* __restrict__ Y2o,
        const float* __restrict__ WaXT, const ushort* __restrict__ XT2,
        float* __restrict__ Gpart) {
    __shared__ __align__(16) char ls[65536];
    const int bx = blockIdx.x;
    if (bx < 256) gemm_sv3<1>(bx, Ws16, Y1T, XT1, Y2T, Y2o, ls);
    else          gram_body(bx - 256, WaXT, XT1, XT2, Gpart, ls);
}

__global__ __launch_bounds__(512, 4) void mega3(const ushort* __restrict__ Ws16,
        const ushort* __restrict__ Y2T, const ushort* __restrict__ Y1T,
        ushort* __restrict__ Y3T, ushort* __restrict__ Y3o,
        const float* __restrict__ Gpart, const float* __restrict__ Thd,
        ushort* __restrict__ DT1, ushort* __restrict__ DT2) {
    __shared__ __align__(16) char ls[65536];
    const int bx = blockIdx.x;
    if (bx < 256) gemm_sv3<1>(bx, Ws16, Y2T, Y1T, Y3T, Y3o, ls);
    else          cheb_body(bx - 256, Gpart, Thd, DT1, DT2, ls);
}

// =================== fused epilogue (unchanged from R8) ===================
__global__ __launch_bounds__(256) void ep_fused(const ushort* __restrict__ ThsT,
                                                const ushort* __restrict__ DT1, const ushort* __restrict__ DT2,
                                                const ushort* __restrict__ X1o, const ushort* __restrict__ X2o,
                                                const ushort* __restrict__ Y1o, const ushort* __restrict__ Y2o,
                                                const ushort* __restrict__ Y3o,
                                                float* __restrict__ out) {
    __shared__ __align__(16) char ls[65536];
    const int b = blockIdx.y, n0 = blockIdx.x * 64;
    const int t = threadIdx.x, lane = t & 63, w = t >> 6, wr = w >> 1, wc = w & 1;
    const int l15 = lane & 15, l4 = lane >> 4;
    stage64x64(X1o + (size_t)n0 * 512 + b * 64, 512, ls + 0 * 8192, t);
    stage64x64(Y1o + (size_t)n0 * 512 + b * 64, 512, ls + 1 * 8192, t);
    stage64x64(Y2o + (size_t)n0 * 512 + b * 64, 512, ls + 2 * 8192, t);
    stage64x64(Y3o + (size_t)n0 * 512 + b * 64, 512, ls + 3 * 8192, t);
    stage64x64(ThsT + 0 * 4096, 64, ls + 4 * 8192, t);
    stage64x64(ThsT + 1 * 4096, 64, ls + 5 * 8192, t);
    stage64x64(ThsT + 2 * 4096, 64, ls + 6 * 8192, t);
    stage64x64(ThsT + 3 * 4096, 64, ls + 7 * 8192, t);
    __syncthreads();
    f32x4 z = {0.f, 0.f, 0.f, 0.f};
    f32x4 as[2][2], ad[2][2];
    as[0][0] = z; as[0][1] = z; as[1][0] = z; as[1][1] = z;
    ad[0][0] = z; ad[0][1] = z; ad[1][0] = z; ad[1][1] = z;
#pragma unroll
    for (int s = 0; s < 2; ++s) {
        const int kb = s * 64 + l4 * 16;
#pragma unroll
        for (int p = 0; p < 4; ++p) {
            bf16x8 aF[2], bF[2];
#pragma unroll
            for (int f = 0; f < 2; ++f) {
                aF[f] = fragld(ls + (4 + p) * 8192, wr * 32 + f * 16 + l15, kb);
                bF[f] = fragld(ls + p * 8192, wc * 32 + f * 16 + l15, kb);
            }
#pragma unroll
            for (int i = 0; i < 2; ++i)
#pragma unroll
                for (int j = 0; j < 2; ++j)
                    as[i][j] = __builtin_amdgcn_mfma_f32_16x16x32_bf16(aF[i], bF[j], as[i][j], 0, 0, 0);
        }
    }
    __syncthreads();
    stage64x64(DT1 + b * 4096, 64, ls + 1 * 8192, t);
    stage64x64(DT2 + b * 4096, 64, ls + 2 * 8192, t);
    stage64x64(X2o + (size_t)n0 * 512 + b * 64, 512, ls + 3 * 8192, t);
    __syncthreads();
#pragma unroll
    for (int s = 0; s < 2; ++s) {
        const int kb = s * 64 + l4 * 16;
        bf16x8 a1[2], a2[2], b0[2], b3[2];
#pragma unroll
        for (int f = 0; f < 2; ++f) {
            a1[f] = fragld(ls + 1 * 8192, wr * 32 + f * 16 + l15, kb);
            a2[f] = fragld(ls + 2 * 8192, wr * 32 + f * 16 + l15, kb);
            b0[f] = fragld(ls + 0 * 8192, wc * 32 + f * 16 + l15, kb);
            b3[f] = fragld(ls + 3 * 8192, wc * 32 + f * 16 + l15, kb);
        }
#pragma unroll
        for (int i = 0; i < 2; ++i)
#pragma unroll
            for (int j = 0; j < 2; ++j) {
                f32x4 a = ad[i][j];
                a = __builtin_amdgcn_mfma_f32_16x16x32_bf16(a1[i], b0[j], a, 0, 0, 0);
                a = __builtin_amdgcn_mfma_f32_16x16x32_bf16(a1[i], b3[j], a, 0, 0, 0);
                a = __builtin_amdgcn_mfma_f32_16x16x32_bf16(a2[i], b0[j], a, 0, 0, 0);
                ad[i][j] = a;
            }
    }
#pragma unroll
    for (int i = 0; i < 2; ++i)
#pragma unroll
        for (int j = 0; j < 2; ++j) {
            const int ob = wr * 32 + i * 16 + l4 * 4;
            const int nn = wc * 32 + j * 16 + l15;
            float4 o4;
            o4.x = fmaxf(as[i][j][0], 0.f) + fmaxf(ad[i][j][0], 0.f);
            o4.y = fmaxf(as[i][j][1], 0.f) + fmaxf(ad[i][j][1], 0.f);
            o4.z = fmaxf(as[i][j][2], 0.f) + fmaxf(ad[i][j][2], 0.f);
            o4.w = fmaxf(as[i][j][3], 0.f) + fmaxf(ad[i][j][3], 0.f);
            *(float4*)&out[((size_t)b * 2048 + n0 + nn) * 64 + ob] = o4;
        }
}

extern "C" void kernel_launch(void* const* d_in, const int* in_sizes, int n_in,
                              void* d_out, int out_size, void* d_ws, size_t ws_size,
                              hipStream_t stream) {
    (void)in_sizes; (void)n_in; (void)out_size;
    const float* X   = (const float*)d_in[0];
    const float* Ws  = (const float*)d_in[1];
    const float* Wa  = (const float*)d_in[2];
    const float* Ths = (const float*)d_in[3];
    const float* Thd = (const float*)d_in[4];

    char* p = (char*)d_ws;
    auto alloc = [&](size_t bytes) { char* r = p; p += (bytes + 255) & ~(size_t)255; return r; };
    ushort* XT1 = (ushort*)alloc(512ull * 2048 * 2);
    ushort* XT2 = (ushort*)alloc(512ull * 2048 * 2);
    ushort* X1o = (ushort*)alloc(2048ull * 512 * 2);
    ushort* X2o = (ushort*)alloc(2048ull * 512 * 2);
    ushort* Ws16 = (ushort*)alloc(2048ull * 2048 * 2);
    ushort* Wa1 = (ushort*)alloc(2048ull * 2048 * 2);
    ushort* Y1T = (ushort*)alloc(512ull * 2048 * 2);
    ushort* Y2T = (ushort*)alloc(512ull * 2048 * 2);
    ushort* Y3T = (ushort*)alloc(512ull * 2048 * 2);
    ushort* Y1o = (ushort*)alloc(2048ull * 512 * 2);
    ushort* Y2o = (ushort*)alloc(2048ull * 512 * 2);
    ushort* Y3o = (ushort*)alloc(2048ull * 512 * 2);
    float*  Gpart = (float*)alloc(32ull * 8 * 4096 * 4);
    ushort* DT1 = (ushort*)alloc(8ull * 4096 * 2);
    ushort* DT2 = (ushort*)alloc(8ull * 4096 * 2);
    ushort* ThsT = (ushort*)alloc(4ull * 4096 * 2);
    if ((size_t)(p - (char*)d_ws) > ws_size) return;   // visible failure if ws too small
    float* WaXT = (float*)d_out;                       // 4MB scratch, overwritten by ep_fused later

    prep_all<<<4416, 256, 0, stream>>>(X, XT1, XT2, X1o, X2o, Ws, Ws16, Wa, Wa1, Ths, ThsT);
    mega1<<<512, 512, 0, stream>>>(Wa1, XT1, XT2, WaXT, Ws16, Y1T, Y1o);
    mega2<<<512, 512, 0, stream>>>(Ws16, Y1T, XT1, Y2T, Y2o, WaXT, XT2, Gpart);
    mega3<<<264, 512, 0, stream>>>(Ws16, Y2T, Y1T, Y3T, Y3o, Gpart, Thd, DT1, DT2);
    ep_fused<<<dim3(32, 8), 256, 0, stream>>>(ThsT, DT1, DT2, X1o, X2o, Y1o, Y2o, Y3o, (float*)d_out);
}

// Round 11
// 86.791 us; speedup vs baseline: 1.0122x; 1.0001x over previous
//
#include <hip/hip_runtime.h>

typedef __attribute__((ext_vector_type(8))) short bf16x8;
typedef __attribute__((ext_vector_type(4))) float f32x4;

__device__ __forceinline__ ushort f32_to_bf16(float f) {
    union { float f; unsigned u; } v; v.f = f;
    unsigned b = v.u + 0x7FFF + ((v.u >> 16) & 1);
    return (ushort)(b >> 16);
}
__device__ __forceinline__ float bf16_to_f32(ushort h) {
    union { unsigned u; float f; } v; v.u = ((unsigned)h) << 16;
    return v.f;
}
__device__ __forceinline__ void split2(float x, ushort& a, ushort& b) {
    a = f32_to_bf16(x); float r1 = x - bf16_to_f32(a);
    b = f32_to_bf16(r1);
}

__device__ __forceinline__ void vmwait4() { asm volatile("s_waitcnt vmcnt(4)" ::: "memory"); }
__device__ __forceinline__ void vmwait3() { asm volatile("s_waitcnt vmcnt(3)" ::: "memory"); }
__device__ __forceinline__ void vmwait0() { asm volatile("s_waitcnt vmcnt(0)" ::: "memory"); }
__device__ __forceinline__ void lgwait0() { asm volatile("s_waitcnt lgkmcnt(0)" ::: "memory"); }
__device__ __forceinline__ void blockbar() {
    __builtin_amdgcn_sched_barrier(0);
    __builtin_amdgcn_s_barrier();
    __builtin_amdgcn_sched_barrier(0);
}

// ---- 64 rows x 128B tile (128B rows), XOR swizzle both sides (rule #21) ----
__device__ __forceinline__ void stage64x64(const ushort* gsrc, int row_stride_elems,
                                           char* lds, int t256) {
    const char* gb = (const char*)gsrc;
    const int rs = row_stride_elems * 2;
#pragma unroll
    for (int j = 0; j < 2; ++j) {
        int o = (j * 256 + t256) * 16;
        int row = o >> 7;
        int col = (o & 127) ^ ((row & 7) << 4);
        __builtin_amdgcn_global_load_lds(
            (const __attribute__((address_space(1))) unsigned int*)(gb + row * rs + col),
            (__attribute__((address_space(3))) unsigned int*)(lds + o), 16, 0, 0);
    }
}
__device__ __forceinline__ bf16x8 fragld(const char* lds, int row, int kbyte) {
    return *(const bf16x8*)(lds + (row << 7) + (kbyte ^ ((row & 7) << 4)));
}

// ---- 64 rows x 64B tile (K=32), row stride 2048 elems, 256 threads x 1 load ----
__device__ __forceinline__ void stage64x32(const ushort* gsrc, char* lds, int t256) {
    const char* gb = (const char*)gsrc;
    int o = t256 * 16;
    int row = o >> 6;
    int col = (o & 63) ^ ((row & 3) << 4);
    __builtin_amdgcn_global_load_lds(
        (const __attribute__((address_space(1))) unsigned int*)(gb + row * 4096 + col),
        (__attribute__((address_space(3))) unsigned int*)(lds + o), 16, 0, 0);
}
__device__ __forceinline__ bf16x8 fragld64(const char* lds, int row, int kbyte) {
    return *(const bf16x8*)(lds + (row << 6) + (kbyte ^ ((row & 3) << 4)));
}

// =================== prep_all (unchanged from R8) ===================
__global__ __launch_bounds__(256) void prep_all(const float* __restrict__ X,
        ushort* __restrict__ XT1, ushort* __restrict__ XT2,
        ushort* __restrict__ X1o, ushort* __restrict__ X2o,
        const float* __restrict__ Ws, ushort* __restrict__ Ws16,
        const float* __restrict__ Wa, ushort* __restrict__ Wa1,
        const float* __restrict__ Ths, ushort* __restrict__ ThsT) {
    __shared__ float tile[64][68];
    const int bx = blockIdx.x;
    const int t = threadIdx.x;
    if (bx < 256) {
        const int b = bx >> 5, n0 = (bx & 31) * 64;
#pragma unroll
        for (int it = 0; it < 4; ++it) {
            int f = it * 256 + t, r = f >> 4, q = (f & 15) * 4;
            float4 v = *(const float4*)&X[((size_t)b * 2048 + n0 + r) * 64 + q];
            tile[r][q + 0] = v.x; tile[r][q + 1] = v.y; tile[r][q + 2] = v.z; tile[r][q + 3] = v.w;
        }
        __syncthreads();
#pragma unroll
        for (int it = 0; it < 4; ++it) {
            int f = it * 256 + t, c = f >> 4, q = (f & 15) * 4;
            ushort4 h1, h2;
            split2(tile[q + 0][c], h1.x, h2.x); split2(tile[q + 1][c], h1.y, h2.y);
            split2(tile[q + 2][c], h1.z, h2.z); split2(tile[q + 3][c], h1.w, h2.w);
            size_t a = (size_t)(b * 64 + c) * 2048 + n0 + q;
            *(ushort4*)&XT1[a] = h1; *(ushort4*)&XT2[a] = h2;
        }
#pragma unroll
        for (int it = 0; it < 4; ++it) {
            int f = it * 256 + t, n = f >> 4, q = (f & 15) * 4;
            ushort4 h1, h2;
            split2(tile[n][q + 0], h1.x, h2.x); split2(tile[n][q + 1], h1.y, h2.y);
            split2(tile[n][q + 2], h1.z, h2.z); split2(tile[n][q + 3], h1.w, h2.w);
            size_t a = (size_t)(n0 + n) * 512 + b * 64 + q;
            *(ushort4*)&X1o[a] = h1; *(ushort4*)&X2o[a] = h2;
        }
    } else if (bx < 2304) {
        size_t idx = ((size_t)(bx - 256) * 256 + t) * 8;
#pragma unroll
        for (int h = 0; h < 2; ++h) {
            float4 v = *(const float4*)&Ws[idx + h * 4];
            ushort4 a;
            a.x = f32_to_bf16(v.x); a.y = f32_to_bf16(v.y);
            a.z = f32_to_bf16(v.z); a.w = f32_to_bf16(v.w);
            *(ushort4*)&Ws16[idx + h * 4] = a;
        }
    } else if (bx < 4352) {
        size_t idx = ((size_t)(bx - 2304) * 256 + t) * 8;
#pragma unroll
        for (int h = 0; h < 2; ++h) {
            float4 v = *(const float4*)&Wa[idx + h * 4];
            ushort4 a;
            a.x = f32_to_bf16(v.x); a.y = f32_to_bf16(v.y);
            a.z = f32_to_bf16(v.z); a.w = f32_to_bf16(v.w);
            *(ushort4*)&Wa1[idx + h * 4] = a;
        }
    } else {
        int idx = (bx - 4352) * 256 + t;
        int k = idx >> 12, o = (idx >> 6) & 63, i = idx & 63;
        ThsT[idx] = f32_to_bf16(Ths[k * 4096 + i * 64 + o]);
    }
}

// =================== gemm_s (R8-proven): 512 thr, 2-phase dbuf, in-block K-split-2 ===================
template <int MODE>
__device__ __forceinline__ void gemm_s_body(int bx, const ushort* __restrict__ A,
        const ushort* __restrict__ BT, const ushort* __restrict__ CinT,
        ushort* __restrict__ YT, ushort* __restrict__ Yo, char* ls) {
    const int t = threadIdx.x;
    const int g = t >> 8, t256 = t & 255;
    const int m0 = (bx & 31) * 64, c0 = (bx >> 5) * 64;
    const int lane = t & 63;
    const int wg = (t >> 6) & 3, wr = wg >> 1, wc = wg & 1;
    const int l15 = lane & 15, l4 = lane >> 4;
    char* base = ls + g * 32768;
    const ushort* Ap = A + (size_t)m0 * 2048 + (size_t)g * 1024;
    const ushort* Bp = BT + (size_t)c0 * 2048 + (size_t)g * 1024;

    f32x4 z = {0.f, 0.f, 0.f, 0.f};
    f32x4 acc[2][2];
    acc[0][0] = z; acc[0][1] = z; acc[1][0] = z; acc[1][1] = z;

    stage64x64(Ap, 2048, base, t256);
    stage64x64(Bp, 2048, base + 8192, t256);
    for (int ts = 0; ts < 16; ++ts) {
        char* cur = base + (ts & 1) * 16384;
        if (ts < 15) {
            char* nxt = base + ((ts + 1) & 1) * 16384;
            stage64x64(Ap + (ts + 1) * 64, 2048, nxt, t256);
            stage64x64(Bp + (ts + 1) * 64, 2048, nxt + 8192, t256);
            vmwait4();
        } else {
            vmwait0();
        }
        blockbar();
#pragma unroll
        for (int s = 0; s < 2; ++s) {
            const int kb = s * 64 + l4 * 16;
            bf16x8 aF[2], bF[2];
#pragma unroll
            for (int f = 0; f < 2; ++f) {
                aF[f] = fragld(cur, wr * 32 + f * 16 + l15, kb);
                bF[f] = fragld(cur + 8192, wc * 32 + f * 16 + l15, kb);
            }
#pragma unroll
            for (int i = 0; i < 2; ++i)
#pragma unroll
                for (int j = 0; j < 2; ++j)
                    acc[i][j] = __builtin_amdgcn_mfma_f32_16x16x32_bf16(aF[i], bF[j], acc[i][j], 0, 0, 0);
        }
        lgwait0();
        blockbar();
    }

    float* red = (float*)ls;
    ushort* tileo = (ushort*)(ls + 17408);
    if (g == 0) {
#pragma unroll
        for (int i = 0; i < 2; ++i)
#pragma unroll
            for (int j = 0; j < 2; ++j) {
                const int lrb = wr * 32 + i * 16 + l4 * 4;
                const int lc = wc * 32 + j * 16 + l15;
#pragma unroll
                for (int r = 0; r < 4; ++r) red[(lrb + r) * 65 + lc] = acc[i][j][r];
            }
    }
    __syncthreads();
    if (g == 1) {
#pragma unroll
        for (int i = 0; i < 2; ++i)
#pragma unroll
            for (int j = 0; j < 2; ++j) {
                const int lrb = wr * 32 + i * 16 + l4 * 4;
                const int lc = wc * 32 + j * 16 + l15;
                float vv[4];
#pragma unroll
                for (int r = 0; r < 4; ++r) vv[r] = red[(lrb + r) * 65 + lc] + acc[i][j][r];
                if (MODE == 1) {
                    ushort4 ci = *(const ushort4*)&CinT[(size_t)(c0 + lc) * 2048 + m0 + lrb];
                    vv[0] = 2.f * vv[0] - bf16_to_f32(ci.x);
                    vv[1] = 2.f * vv[1] - bf16_to_f32(ci.y);
                    vv[2] = 2.f * vv[2] - bf16_to_f32(ci.z);
                    vv[3] = 2.f * vv[3] - bf16_to_f32(ci.w);
                }
                ushort4 p;
                p.x = f32_to_bf16(vv[0]); p.y = f32_to_bf16(vv[1]);
                p.z = f32_to_bf16(vv[2]); p.w = f32_to_bf16(vv[3]);
                *(ushort4*)&YT[(size_t)(c0 + lc) * 2048 + m0 + lrb] = p;
                tileo[(lrb + 0) * 64 + lc] = p.x;
                tileo[(lrb + 1) * 64 + lc] = p.y;
                tileo[(lrb + 2) * 64 + lc] = p.z;
                tileo[(lrb + 3) * 64 + lc] = p.w;
            }
    }
    __syncthreads();
    {
        int row = t >> 3, ch = t & 7;
        *(uint4*)&Yo[(size_t)(m0 + row) * 512 + c0 + ch * 8] = *(uint4*)&tileo[row * 64 + ch * 8];
    }
}

// =================== y3 body (R6-proven): split-K-2 across block pairs -> f32 P0/P1 ===================
__device__ __forceinline__ void y3_body(int bx, const ushort* __restrict__ A,
        const ushort* __restrict__ BT, float* __restrict__ P0, float* __restrict__ P1,
        char* ls) {
    const int t = threadIdx.x;
    const int g = t >> 8, t256 = t & 255;
    const int tile = bx >> 1, g2 = bx & 1;
    const int m0 = (tile & 31) * 64, c0 = (tile >> 5) * 64;
    const int lane = t & 63;
    const int wg = (t >> 6) & 3, wr = wg >> 1, wc = wg & 1;
    const int l15 = lane & 15, l4 = lane >> 4;
    char* base = ls + g * 32768;
    const size_t kbase = (size_t)g2 * 1024 + (size_t)g * 512;
    const ushort* Ap = A + (size_t)m0 * 2048 + kbase;
    const ushort* Bp = BT + (size_t)c0 * 2048 + kbase;

    f32x4 z = {0.f, 0.f, 0.f, 0.f};
    f32x4 acc[2][2];
    acc[0][0] = z; acc[0][1] = z; acc[1][0] = z; acc[1][1] = z;

    stage64x64(Ap, 2048, base, t256);
    stage64x64(Bp, 2048, base + 8192, t256);
    for (int ts = 0; ts < 8; ++ts) {
        char* cur = base + (ts & 1) * 16384;
        if (ts < 7) {
            char* nxt = base + ((ts + 1) & 1) * 16384;
            stage64x64(Ap + (ts + 1) * 64, 2048, nxt, t256);
            stage64x64(Bp + (ts + 1) * 64, 2048, nxt + 8192, t256);
            vmwait4();
        } else {
            vmwait0();
        }
        blockbar();
#pragma unroll
        for (int s = 0; s < 2; ++s) {
            const int kb = s * 64 + l4 * 16;
            bf16x8 aF[2], bF[2];
#pragma unroll
            for (int f = 0; f < 2; ++f) {
                aF[f] = fragld(cur, wr * 32 + f * 16 + l15, kb);
                bF[f] = fragld(cur + 8192, wc * 32 + f * 16 + l15, kb);
            }
#pragma unroll
            for (int i = 0; i < 2; ++i)
#pragma unroll
                for (int j = 0; j < 2; ++j)
                    acc[i][j] = __builtin_amdgcn_mfma_f32_16x16x32_bf16(aF[i], bF[j], acc[i][j], 0, 0, 0);
        }
        lgwait0();
        blockbar();
    }

    float* red = (float*)ls;
    float* tf = (float*)(ls + 17408);
    if (g == 0) {
#pragma unroll
        for (int i = 0; i < 2; ++i)
#pragma unroll
            for (int j = 0; j < 2; ++j) {
                const int lrb = wr * 32 + i * 16 + l4 * 4;
                const int lc = wc * 32 + j * 16 + l15;
#pragma unroll
                for (int r = 0; r < 4; ++r) red[(lrb + r) * 65 + lc] = acc[i][j][r];
            }
    }
    __syncthreads();
    if (g == 1) {
#pragma unroll
        for (int i = 0; i < 2; ++i)
#pragma unroll
            for (int j = 0; j < 2; ++j) {
                const int lrb = wr * 32 + i * 16 + l4 * 4;
                const int lc = wc * 32 + j * 16 + l15;
#pragma unroll
                for (int r = 0; r < 4; ++r) tf[(lrb + r) * 64 + lc] = red[(lrb + r) * 65 + lc] + acc[i][j][r];
            }
    }
    __syncthreads();
    {
        float* Pd = g2 ? P1 : P0;
        int row = t >> 3, q = (t & 7) * 8;
        *(float4*)&Pd[(size_t)(m0 + row) * 512 + c0 + q]     = *(float4*)&tf[row * 64 + q];
        *(float4*)&Pd[(size_t)(m0 + row) * 512 + c0 + q + 4] = *(float4*)&tf[row * 64 + q + 4];
    }
}

// =================== gemm3 v4: pipelined, K-step 32, dbuf 2x12KB per group ===================
__device__ __forceinline__ void gemm3v4(int bx, const ushort* __restrict__ A1,
        const ushort* __restrict__ B1, const ushort* __restrict__ B2,
        float* __restrict__ WaXT, char* ls) {
    const int t = threadIdx.x;
    const int g = t >> 8, t256 = t & 255;
    const int m0 = (bx & 31) * 64, c0 = (bx >> 5) * 64;
    const int lane = t & 63;
    const int wg = (t >> 6) & 3, wr = wg >> 1, wc = wg & 1;
    const int l15 = lane & 15, l4 = lane >> 4;
    char* gbase = ls + g * 24576;           // 2 bufs x 12KB (A|B1|B2 x 4KB)
    const int kb = l4 * 16;                 // 16B slice of 64B K-row
    const ushort* Ap = A1 + (size_t)m0 * 2048 + (size_t)g * 1024;
    const ushort* B1p = B1 + (size_t)c0 * 2048 + (size_t)g * 1024;
    const ushort* B2p = B2 + (size_t)c0 * 2048 + (size_t)g * 1024;

    f32x4 z = {0.f, 0.f, 0.f, 0.f};
    f32x4 acc[2][2];
    acc[0][0] = z; acc[0][1] = z; acc[1][0] = z; acc[1][1] = z;

    stage64x32(Ap, gbase, t256);
    stage64x32(B1p, gbase + 4096, t256);
    stage64x32(B2p, gbase + 8192, t256);
    for (int ts = 0; ts < 32; ++ts) {
        char* cur = gbase + (ts & 1) * 12288;
        if (ts < 31) {
            char* nxt = gbase + ((ts + 1) & 1) * 12288;
            stage64x32(Ap + (ts + 1) * 32, nxt, t256);
            stage64x32(B1p + (ts + 1) * 32, nxt + 4096, t256);
            stage64x32(B2p + (ts + 1) * 32, nxt + 8192, t256);
            vmwait3();                      // my 3 loads for cur are done
        } else {
            vmwait0();
        }
        blockbar();
        bf16x8 aF[2], b1F[2], b2F[2];
#pragma unroll
        for (int f = 0; f < 2; ++f) {
            aF[f]  = fragld64(cur, wr * 32 + f * 16 + l15, kb);
            b1F[f] = fragld64(cur + 4096, wc * 32 + f * 16 + l15, kb);
            b2F[f] = fragld64(cur + 8192, wc * 32 + f * 16 + l15, kb);
        }
#pragma unroll
        for (int i = 0; i < 2; ++i)
#pragma unroll
            for (int j = 0; j < 2; ++j) {
                f32x4 a = acc[i][j];
                a = __builtin_amdgcn_mfma_f32_16x16x32_bf16(aF[i], b1F[j], a, 0, 0, 0);
                a = __builtin_amdgcn_mfma_f32_16x16x32_bf16(aF[i], b2F[j], a, 0, 0, 0);
                acc[i][j] = a;
            }
        lgwait0();
        blockbar();
    }

    float* red = (float*)ls;
    if (g == 0) {
#pragma unroll
        for (int i = 0; i < 2; ++i)
#pragma unroll
            for (int j = 0; j < 2; ++j) {
                const int lrb = wr * 32 + i * 16 + l4 * 4;
                const int lc = wc * 32 + j * 16 + l15;
#pragma unroll
                for (int r = 0; r < 4; ++r) red[(lrb + r) * 65 + lc] = acc[i][j][r];
            }
    }
    __syncthreads();
    if (g == 1) {
#pragma unroll
        for (int i = 0; i < 2; ++i)
#pragma unroll
            for (int j = 0; j < 2; ++j) {
                const int lrb = wr * 32 + i * 16 + l4 * 4;
                const int lc = wc * 32 + j * 16 + l15;
                f32x4 v;
#pragma unroll
                for (int r = 0; r < 4; ++r) v[r] = red[(lrb + r) * 65 + lc] + acc[i][j][r];
                *(f32x4*)&WaXT[(size_t)(c0 + lc) * 2048 + m0 + lrb] = v;
            }
    }
}

// =================== gram body (R8) ===================
__device__ __forceinline__ void gram_body(int bx, const float* __restrict__ WaXT,
        const ushort* __restrict__ XT1, const ushort* __restrict__ XT2,
        float* __restrict__ Gpart, char* lsraw) {
    const int b = bx & 7, chunk = bx >> 3;
    float (*Lw)[68] = (float(*)[68])lsraw;
    float (*Rx)[68] = (float(*)[68])(lsraw + 64 * 68 * 4);
    const int t = threadIdx.x;
    const int n0 = chunk * 64;
    {
        const int r = t >> 3, q = (t & 7) * 8;
        size_t a = (size_t)(b * 64 + r) * 2048 + n0 + q;
        *(float4*)&Lw[r][q]     = *(const float4*)&WaXT[a];
        *(float4*)&Lw[r][q + 4] = *(const float4*)&WaXT[a + 4];
#pragma unroll
        for (int h = 0; h < 2; ++h) {
            ushort4 h1 = *(const ushort4*)&XT1[a + h * 4];
            ushort4 h2 = *(const ushort4*)&XT2[a + h * 4];
            Rx[r][q + h * 4 + 0] = bf16_to_f32(h1.x) + bf16_to_f32(h2.x);
            Rx[r][q + h * 4 + 1] = bf16_to_f32(h1.y) + bf16_to_f32(h2.y);
            Rx[r][q + h * 4 + 2] = bf16_to_f32(h1.z) + bf16_to_f32(h2.z);
            Rx[r][q + h * 4 + 3] = bf16_to_f32(h1.w) + bf16_to_f32(h2.w);
        }
    }
    __syncthreads();
    if (t < 256) {
        const int tx = t & 15, ty = t >> 4;
        float acc[4][4] = {{0.f,0.f,0.f,0.f},{0.f,0.f,0.f,0.f},{0.f,0.f,0.f,0.f},{0.f,0.f,0.f,0.f}};
        for (int n = 0; n < 64; ++n) {
            float a[4], bb[4];
#pragma unroll
            for (int i = 0; i < 4; ++i) { a[i] = Lw[ty * 4 + i][n]; bb[i] = Rx[tx * 4 + i][n]; }
#pragma unroll
            for (int i = 0; i < 4; ++i)
#pragma unroll
                for (int j = 0; j < 4; ++j) acc[i][j] = fmaf(a[i], bb[j], acc[i][j]);
        }
        float* gp = Gpart + (size_t)(chunk * 8 + b) * 4096;
#pragma unroll
        for (int i = 0; i < 4; ++i)
            *(float4*)&gp[(ty * 4 + i) * 64 + tx * 4] =
                make_float4(acc[i][0], acc[i][1], acc[i][2], acc[i][3]);
    }
}

// =================== cheb body (R8) ===================
__device__ __forceinline__ void cheb_body(int b, const float* __restrict__ Gpart,
        const float* __restrict__ Thd, ushort* __restrict__ DT1, ushort* __restrict__ DT2,
        char* lsraw) {
    float (*Gs)[68]  = (float(*)[68])lsraw;
    float (*C2s)[68] = (float(*)[68])(lsraw + 17408);
    float (*C3s)[68] = (float(*)[68])(lsraw + 34816);
    const int t = threadIdx.x;
    for (int i = t; i < 4096; i += 512) {
        float s = 0.f;
#pragma unroll
        for (int c = 0; c < 32; ++c) s += Gpart[((size_t)c * 8 + b) * 4096 + i];
        Gs[i >> 6][i & 63] = s;
    }
    __syncthreads();
    const int tx = t & 15, ty = (t >> 4) & 15;
    const int r0 = ty * 4, c0 = tx * 4;
    const bool act = t < 256;

    if (act) {
        float p[4][4] = {{0,0,0,0},{0,0,0,0},{0,0,0,0},{0,0,0,0}};
        for (int k = 0; k < 64; ++k) {
            float ar[4] = {Gs[r0][k], Gs[r0+1][k], Gs[r0+2][k], Gs[r0+3][k]};
            float4 bv = *(const float4*)&Gs[k][c0];
            float br[4] = {bv.x, bv.y, bv.z, bv.w};
#pragma unroll
            for (int i = 0; i < 4; ++i)
#pragma unroll
                for (int j = 0; j < 4; ++j) p[i][j] = fmaf(ar[i], br[j], p[i][j]);
        }
#pragma unroll
        for (int i = 0; i < 4; ++i)
#pragma unroll
            for (int j = 0; j < 4; ++j)
                C2s[r0+i][c0+j] = 2.f * p[i][j] - ((r0+i) == (c0+j) ? 1.f : 0.f);
    }
    __syncthreads();
    if (act) {
        float q[4][4] = {{0,0,0,0},{0,0,0,0},{0,0,0,0},{0,0,0,0}};
        for (int k = 0; k < 64; ++k) {
            float ar[4] = {Gs[r0][k], Gs[r0+1][k], Gs[r0+2][k], Gs[r0+3][k]};
            float4 bv = *(const float4*)&C2s[k][c0];
            float br[4] = {bv.x, bv.y, bv.z, bv.w};
#pragma unroll
            for (int i = 0; i < 4; ++i)
#pragma unroll
                for (int j = 0; j < 4; ++j) q[i][j] = fmaf(ar[i], br[j], q[i][j]);
        }
#pragma unroll
        for (int i = 0; i < 4; ++i)
#pragma unroll
            for (int j = 0; j < 4; ++j)
                C3s[r0+i][c0+j] = 2.f * q[i][j] - Gs[r0+i][c0+j];
    }
    __syncthreads();
    float d[4][4];
    if (act) {
#pragma unroll
        for (int i = 0; i < 4; ++i) {
            float4 t0 = *(const float4*)&Thd[(r0+i) * 64 + c0];
            d[i][0] = t0.x; d[i][1] = t0.y; d[i][2] = t0.z; d[i][3] = t0.w;
        }
        for (int k = 0; k < 64; ++k) {
            float4 t1 = *(const float4*)&Thd[4096 + k * 64 + c0];
            float4 t2 = *(const float4*)&Thd[8192 + k * 64 + c0];
            float4 t3 = *(const float4*)&Thd[12288 + k * 64 + c0];
            float a1[4] = {Gs[r0][k], Gs[r0+1][k], Gs[r0+2][k], Gs[r0+3][k]};
            float a2[4] = {C2s[r0][k], C2s[r0+1][k], C2s[r0+2][k], C2s[r0+3][k]};
            float a3[4] = {C3s[r0][k], C3s[r0+1][k], C3s[r0+2][k], C3s[r0+3][k]};
            float b1[4] = {t1.x, t1.y, t1.z, t1.w};
            float b2[4] = {t2.x, t2.y, t2.z, t2.w};
            float b3[4] = {t3.x, t3.y, t3.z, t3.w};
#pragma unroll
            for (int i = 0; i < 4; ++i)
#pragma unroll
                for (int j = 0; j < 4; ++j) {
                    d[i][j] = fmaf(a1[i], b1[j], d[i][j]);
                    d[i][j] = fmaf(a2[i], b2[j], d[i][j]);
                    d[i][j] = fmaf(a3[i], b3[j], d[i][j]);
                }
        }
    }
    __syncthreads();
    if (act) {
#pragma unroll
        for (int i = 0; i < 4; ++i)
#pragma unroll
            for (int j = 0; j < 4; ++j) Gs[r0 + i][c0 + j] = d[i][j];
    }
    __syncthreads();
    for (int it = 0; it < 8; ++it) {
        int idx = it * 512 + t;              // o*64 + i (transposed emit)
        int o = idx >> 6, ii = idx & 63;
        ushort h1, h2;
        split2(Gs[ii][o], h1, h2);
        DT1[b * 4096 + idx] = h1;
        DT2[b * 4096 + idx] = h2;
    }
}

// =================== mega kernels ===================
__global__ __launch_bounds__(512, 4) void mega1(const ushort* __restrict__ Wa1,
        const ushort* __restrict__ XT1, const ushort* __restrict__ XT2,
        float* __restrict__ WaXT,
        const ushort* __restrict__ Ws16, ushort* __restrict__ Y1T, ushort* __restrict__ Y1o) {
    __shared__ __align__(16) char ls[65536];
    const int bx = blockIdx.x;
    if (bx < 256) gemm3v4(bx, Wa1, XT1, XT2, WaXT, ls);
    else          gemm_s_body<0>(bx - 256, Ws16, XT1, nullptr, Y1T, Y1o, ls);
}

__global__ __launch_bounds__(512, 4) void mega2(const ushort* __restrict__ Ws16,
        const ushort* __restrict__ Y1T, const ushort* __restrict__ XT1,
        ushort* __restrict__ Y2T, ushort* __restrict__ Y2o,
        const float* __restrict__ WaXT, const ushort* __restrict__ XT2,
        float* __restrict__ Gpart) {
    __shared__ __align__(16) char ls[65536];
    const int bx = blockIdx.x;
    if (bx < 256) gemm_s_body<1>(bx, Ws16, Y1T, XT1, Y2T, Y2o, ls);
    else          gram_body(bx - 256, WaXT, XT1, XT2, Gpart, ls);
}

__global__ __launch_bounds__(512, 4) void mega3(const ushort* __restrict__ Ws16,
        const ushort* __restrict__ Y2T, float* __restrict__ P0, float* __restrict__ P1,
        const float* __restrict__ Gpart, const float* __restrict__ Thd,
        ushort* __restrict__ DT1, ushort* __restrict__ DT2) {
    __shared__ __align__(16) char ls[65536];
    const int bx = blockIdx.x;
    if (bx < 8) cheb_body(bx, Gpart, Thd, DT1, DT2, ls);   // cheb first: co-resident at t=0
    else        y3_body(bx - 8, Ws16, Y2T, P0, P1, ls);
}

// =================== fused epilogue (R6-proven): Y3 combine folded in ===================
__global__ __launch_bounds__(256) void ep_fused(const ushort* __restrict__ ThsT,
                                                const ushort* __restrict__ DT1, const ushort* __restrict__ DT2,
                                                const ushort* __restrict__ X1o, const ushort* __restrict__ X2o,
                                                const ushort* __restrict__ Y1o, const ushort* __restrict__ Y2o,
                                                const float* __restrict__ P0, const float* __restrict__ P1,
                                                float* __restrict__ out) {
    __shared__ __align__(16) char ls[65536];
    const int b = blockIdx.y, n0 = blockIdx.x * 64;
    const int t = threadIdx.x, lane = t & 63, w = t >> 6, wr = w >> 1, wc = w & 1;
    const int l15 = lane & 15, l4 = lane >> 4;

    // early reg loads for Y3 combine (16 elems/thread: row r3, cols q3e..q3e+15)
    const int r3 = t >> 2, q3e = (t & 3) * 16;
    const size_t a3 = (size_t)(n0 + r3) * 512 + b * 64 + q3e;
    float4 pA[4], pB[4];
    ushort4 y1v[4];
#pragma unroll
    for (int h = 0; h < 4; ++h) {
        pA[h]  = *(const float4*)&P0[a3 + h * 4];
        pB[h]  = *(const float4*)&P1[a3 + h * 4];
        y1v[h] = *(const ushort4*)&Y1o[a3 + h * 4];
    }

    stage64x64(X1o + (size_t)n0 * 512 + b * 64, 512, ls + 0 * 8192, t);
    stage64x64(Y1o + (size_t)n0 * 512 + b * 64, 512, ls + 1 * 8192, t);
    stage64x64(Y2o + (size_t)n0 * 512 + b * 64, 512, ls + 2 * 8192, t);
    stage64x64(ThsT + 0 * 4096, 64, ls + 4 * 8192, t);
    stage64x64(ThsT + 1 * 4096, 64, ls + 5 * 8192, t);
    stage64x64(ThsT + 2 * 4096, 64, ls + 6 * 8192, t);
    stage64x64(ThsT + 3 * 4096, 64, ls + 7 * 8192, t);
    {   // slot 3: Y3 = 2*(P0+P1) - Y1 -> bf16, swizzled ds_write (two 16B words)
        uint4 w0, w1;
        ushort* u0 = (ushort*)&w0;
        ushort* u1 = (ushort*)&w1;
#pragma unroll
        for (int h = 0; h < 2; ++h) {
            const float4 pa = pA[h], pb = pB[h];
            const ushort4 yv = y1v[h];
            u0[h * 4 + 0] = f32_to_bf16(2.f * (pa.x + pb.x) - bf16_to_f32(yv.x));
            u0[h * 4 + 1] = f32_to_bf16(2.f * (pa.y + pb.y) - bf16_to_f32(yv.y));
            u0[h * 4 + 2] = f32_to_bf16(2.f * (pa.z + pb.z) - bf16_to_f32(yv.z));
            u0[h * 4 + 3] = f32_to_bf16(2.f * (pa.w + pb.w) - bf16_to_f32(yv.w));
        }
#pragma unroll
        for (int h = 0; h < 2; ++h) {
            const float4 pa = pA[2 + h], pb = pB[2 + h];
            const ushort4 yv = y1v[2 + h];
            u1[h * 4 + 0] = f32_to_bf16(2.f * (pa.x + pb.x) - bf16_to_f32(yv.x));
            u1[h * 4 + 1] = f32_to_bf16(2.f * (pa.y + pb.y) - bf16_to_f32(yv.y));
            u1[h * 4 + 2] = f32_to_bf16(2.f * (pa.z + pb.z) - bf16_to_f32(yv.z));
            u1[h * 4 + 3] = f32_to_bf16(2.f * (pa.w + pb.w) - bf16_to_f32(yv.w));
        }
        const int bc0 = q3e * 2;               // byte col {0,32,64,96}
        const int sw = (r3 & 7) << 4;
        *(uint4*)(ls + 3 * 8192 + (r3 << 7) + ((bc0 + 0)  ^ sw)) = w0;
        *(uint4*)(ls + 3 * 8192 + (r3 << 7) + ((bc0 + 16) ^ sw)) = w1;
    }
    __syncthreads();

    f32x4 z = {0.f, 0.f, 0.f, 0.f};
    f32x4 as[2][2], ad[2][2];
    as[0][0] = z; as[0][1] = z; as[1][0] = z; as[1][1] = z;
    ad[0][0] = z; ad[0][1] = z; ad[1][0] = z; ad[1][1] = z;
#pragma unroll
    for (int s = 0; s < 2; ++s) {
        const int kb = s * 64 + l4 * 16;
#pragma unroll
        for (int p = 0; p < 4; ++p) {
            bf16x8 aF[2], bF[2];
#pragma unroll
            for (int f = 0; f < 2; ++f) {
                aF[f] = fragld(ls + (4 + p) * 8192, wr * 32 + f * 16 + l15, kb);
                bF[f] = fragld(ls + p * 8192, wc * 32 + f * 16 + l15, kb);
            }
#pragma unroll
            for (int i = 0; i < 2; ++i)
#pragma unroll
                for (int j = 0; j < 2; ++j)
                    as[i][j] = __builtin_amdgcn_mfma_f32_16x16x32_bf16(aF[i], bF[j], as[i][j], 0, 0, 0);
        }
    }
    __syncthreads();
    stage64x64(DT1 + b * 4096, 64, ls + 1 * 8192, t);
    stage64x64(DT2 + b * 4096, 64, ls + 2 * 8192, t);
    stage64x64(X2o + (size_t)n0 * 512 + b * 64, 512, ls + 3 * 8192, t);
    __syncthreads();
#pragma unroll
    for (int s = 0; s < 2; ++s) {
        const int kb = s * 64 + l4 * 16;
        bf16x8 a1[2], a2[2], b0[2], b3[2];
#pragma unroll
        for (int f = 0; f < 2; ++f) {
            a1[f] = fragld(ls + 1 * 8192, wr * 32 + f * 16 + l15, kb);
            a2[f] = fragld(ls + 2 * 8192, wr * 32 + f * 16 + l15, kb);
            b0[f] = fragld(ls + 0 * 8192, wc * 32 + f * 16 + l15, kb);
            b3[f] = fragld(ls + 3 * 8192, wc * 32 + f * 16 + l15, kb);
        }
#pragma unroll
        for (int i = 0; i < 2; ++i)
#pragma unroll
            for (int j = 0; j < 2; ++j) {
                f32x4 a = ad[i][j];
                a = __builtin_amdgcn_mfma_f32_16x16x32_bf16(a1[i], b0[j], a, 0, 0, 0);
                a = __builtin_amdgcn_mfma_f32_16x16x32_bf16(a1[i], b3[j], a, 0, 0, 0);
                a = __builtin_amdgcn_mfma_f32_16x16x32_bf16(a2[i], b0[j], a, 0, 0, 0);
                ad[i][j] = a;
            }
    }
#pragma unroll
    for (int i = 0; i < 2; ++i)
#pragma unroll
        for (int j = 0; j < 2; ++j) {
            const int ob = wr * 32 + i * 16 + l4 * 4;
            const int nn = wc * 32 + j * 16 + l15;
            float4 o4;
            o4.x = fmaxf(as[i][j][0], 0.f) + fmaxf(ad[i][j][0], 0.f);
            o4.y = fmaxf(as[i][j][1], 0.f) + fmaxf(ad[i][j][1], 0.f);
            o4.z = fmaxf(as[i][j][2], 0.f) + fmaxf(ad[i][j][2], 0.f);
            o4.w = fmaxf(as[i][j][3], 0.f) + fmaxf(ad[i][j][3], 0.f);
            *(float4*)&out[((size_t)b * 2048 + n0 + nn) * 64 + ob] = o4;
        }
}

extern "C" void kernel_launch(void* const* d_in, const int* in_sizes, int n_in,
                              void* d_out, int out_size, void* d_ws, size_t ws_size,
                              hipStream_t stream) {
    (void)in_sizes; (void)n_in; (void)out_size;
    const float* X   = (const float*)d_in[0];
    const float* Ws  = (const float*)d_in[1];
    const float* Wa  = (const float*)d_in[2];
    const float* Ths = (const float*)d_in[3];
    const float* Thd = (const float*)d_in[4];

    char* p = (char*)d_ws;
    auto alloc = [&](size_t bytes) { char* r = p; p += (bytes + 255) & ~(size_t)255; return r; };
    ushort* XT1 = (ushort*)alloc(512ull * 2048 * 2);
    ushort* XT2 = (ushort*)alloc(512ull * 2048 * 2);
    ushort* X1o = (ushort*)alloc(2048ull * 512 * 2);
    ushort* X2o = (ushort*)alloc(2048ull * 512 * 2);
    ushort* Ws16 = (ushort*)alloc(2048ull * 2048 * 2);
    ushort* Wa1 = (ushort*)alloc(2048ull * 2048 * 2);
    ushort* Y1T = (ushort*)alloc(512ull * 2048 * 2);
    ushort* Y2T = (ushort*)alloc(512ull * 2048 * 2);
    ushort* Y1o = (ushort*)alloc(2048ull * 512 * 2);
    ushort* Y2o = (ushort*)alloc(2048ull * 512 * 2);
    float*  P0  = (float*)alloc(2048ull * 512 * 4);
    float*  P1  = (float*)alloc(2048ull * 512 * 4);
    float*  Gpart = (float*)alloc(32ull * 8 * 4096 * 4);
    ushort* DT1 = (ushort*)alloc(8ull * 4096 * 2);
    ushort* DT2 = (ushort*)alloc(8ull * 4096 * 2);
    ushort* ThsT = (ushort*)alloc(4ull * 4096 * 2);
    if ((size_t)(p - (char*)d_ws) > ws_size) return;   // visible failure if ws too small
    float* WaXT = (float*)d_out;                       // 4MB scratch, overwritten by ep_fused later

    prep_all<<<4416, 256, 0, stream>>>(X, XT1, XT2, X1o, X2o, Ws, Ws16, Wa, Wa1, Ths, ThsT);
    mega1<<<512, 512, 0, stream>>>(Wa1, XT1, XT2, WaXT, Ws16, Y1T, Y1o);
    mega2<<<512, 512, 0, stream>>>(Ws16, Y1T, XT1, Y2T, Y2o, WaXT, XT2, Gpart);
    mega3<<<520, 512, 0, stream>>>(Ws16, Y2T, P0, P1, Gpart, Thd, DT1, DT2);
    ep_fused<<<dim3(32, 8), 256, 0, stream>>>(ThsT, DT1, DT2, X1o, X2o, Y1o, Y2o, P0, P1, (float*)d_out);
}

// Round 13
// 82.660 us; speedup vs baseline: 1.0627x; 1.0500x over previous
//
#include <hip/hip_runtime.h>

typedef __attribute__((ext_vector_type(8))) short bf16x8;
typedef __attribute__((ext_vector_type(4))) float f32x4;

__device__ __forceinline__ ushort f32_to_bf16(float f) {
    union { float f; unsigned u; } v; v.f = f;
    unsigned b = v.u + 0x7FFF + ((v.u >> 16) & 1);
    return (ushort)(b >> 16);
}
__device__ __forceinline__ float bf16_to_f32(ushort h) {
    union { unsigned u; float f; } v; v.u = ((unsigned)h) << 16;
    return v.f;
}
__device__ __forceinline__ void split2(float x, ushort& a, ushort& b) {
    a = f32_to_bf16(x); float r1 = x - bf16_to_f32(a);
    b = f32_to_bf16(r1);
}

__device__ __forceinline__ void vmwait4() { asm volatile("s_waitcnt vmcnt(4)" ::: "memory"); }
__device__ __forceinline__ void vmwait0() { asm volatile("s_waitcnt vmcnt(0)" ::: "memory"); }
__device__ __forceinline__ void lgwait0() { asm volatile("s_waitcnt lgkmcnt(0)" ::: "memory"); }
__device__ __forceinline__ void blockbar() {
    __builtin_amdgcn_sched_barrier(0);
    __builtin_amdgcn_s_barrier();
    __builtin_amdgcn_sched_barrier(0);
}

// 64 rows x 128B tile global->LDS, XOR swizzle via global source (rule #21), t256 in [0,256)
__device__ __forceinline__ void stage64x64(const ushort* gsrc, int row_stride_elems,
                                           char* lds, int t256) {
    const char* gb = (const char*)gsrc;
    const int rs = row_stride_elems * 2;
#pragma unroll
    for (int j = 0; j < 2; ++j) {
        int o = (j * 256 + t256) * 16;
        int row = o >> 7;
        int col = (o & 127) ^ ((row & 7) << 4);
        __builtin_amdgcn_global_load_lds(
            (const __attribute__((address_space(1))) unsigned int*)(gb + row * rs + col),
            (__attribute__((address_space(3))) unsigned int*)(lds + o), 16, 0, 0);
    }
}

__device__ __forceinline__ bf16x8 fragld(const char* lds, int row, int kbyte) {
    return *(const bf16x8*)(lds + (row << 7) + (kbyte ^ ((row & 7) << 4)));
}

// =================== prep_all: fused prep_xt / conv_ws / conv_wa / conv_tht ===================
__global__ __launch_bounds__(256) void prep_all(const float* __restrict__ X,
        ushort* __restrict__ XT1, ushort* __restrict__ XT2,
        ushort* __restrict__ X1o, ushort* __restrict__ X2o,
        const float* __restrict__ Ws, ushort* __restrict__ Ws16,
        const float* __restrict__ Wa, ushort* __restrict__ Wa1,
        const float* __restrict__ Ths, ushort* __restrict__ ThsT) {
    __shared__ float tile[64][68];
    const int bx = blockIdx.x;
    const int t = threadIdx.x;
    if (bx < 256) {                       // ---- prep_xt ----
        const int b = bx >> 5, n0 = (bx & 31) * 64;
#pragma unroll
        for (int it = 0; it < 4; ++it) {
            int f = it * 256 + t, r = f >> 4, q = (f & 15) * 4;
            float4 v = *(const float4*)&X[((size_t)b * 2048 + n0 + r) * 64 + q];
            tile[r][q + 0] = v.x; tile[r][q + 1] = v.y; tile[r][q + 2] = v.z; tile[r][q + 3] = v.w;
        }
        __syncthreads();
#pragma unroll
        for (int it = 0; it < 4; ++it) {  // T-layout: row = b*64+c, cols n
            int f = it * 256 + t, c = f >> 4, q = (f & 15) * 4;
            ushort4 h1, h2;
            split2(tile[q + 0][c], h1.x, h2.x); split2(tile[q + 1][c], h1.y, h2.y);
            split2(tile[q + 2][c], h1.z, h2.z); split2(tile[q + 3][c], h1.w, h2.w);
            size_t a = (size_t)(b * 64 + c) * 2048 + n0 + q;
            *(ushort4*)&XT1[a] = h1; *(ushort4*)&XT2[a] = h2;
        }
#pragma unroll
        for (int it = 0; it < 4; ++it) {  // orig layout: row n, cols bc
            int f = it * 256 + t, n = f >> 4, q = (f & 15) * 4;
            ushort4 h1, h2;
            split2(tile[n][q + 0], h1.x, h2.x); split2(tile[n][q + 1], h1.y, h2.y);
            split2(tile[n][q + 2], h1.z, h2.z); split2(tile[n][q + 3], h1.w, h2.w);
            size_t a = (size_t)(n0 + n) * 512 + b * 64 + q;
            *(ushort4*)&X1o[a] = h1; *(ushort4*)&X2o[a] = h2;
        }
    } else if (bx < 2304) {               // ---- conv_ws: 8 elems/thread ----
        size_t idx = ((size_t)(bx - 256) * 256 + t) * 8;
#pragma unroll
        for (int h = 0; h < 2; ++h) {
            float4 v = *(const float4*)&Ws[idx + h * 4];
            ushort4 a;
            a.x = f32_to_bf16(v.x); a.y = f32_to_bf16(v.y);
            a.z = f32_to_bf16(v.z); a.w = f32_to_bf16(v.w);
            *(ushort4*)&Ws16[idx + h * 4] = a;
        }
    } else if (bx < 4352) {               // ---- conv_wa: plain bf16 (no residual) ----
        size_t idx = ((size_t)(bx - 2304) * 256 + t) * 8;
#pragma unroll
        for (int h = 0; h < 2; ++h) {
            float4 v = *(const float4*)&Wa[idx + h * 4];
            ushort4 a;
            a.x = f32_to_bf16(v.x); a.y = f32_to_bf16(v.y);
            a.z = f32_to_bf16(v.z); a.w = f32_to_bf16(v.w);
            *(ushort4*)&Wa1[idx + h * 4] = a;
        }
    } else {                              // ---- conv_tht (transpose Theta_s) ----
        int idx = (bx - 4352) * 256 + t;  // k*4096 + o*64 + i
        int k = idx >> 12, o = (idx >> 6) & 63, i = idx & 63;
        ThsT[idx] = f32_to_bf16(Ths[k * 4096 + i * 64 + o]);
    }
}

// =================== gemm_s body: 2-phase dbuf pipeline, in-block K-split ===================
template <int MODE>
__device__ __forceinline__ void gemm_s_body(int bx, const ushort* __restrict__ A,
        const ushort* __restrict__ BT, const ushort* __restrict__ CinT,
        ushort* __restrict__ YT, ushort* __restrict__ Yo, char* ls) {
    const int t = threadIdx.x;
    const int g = t >> 8, t256 = t & 255;
    const int m0 = (bx & 31) * 64, c0 = (bx >> 5) * 64;
    const int lane = t & 63;
    const int wg = (t >> 6) & 3, wr = wg >> 1, wc = wg & 1;
    const int l15 = lane & 15, l4 = lane >> 4;
    char* base = ls + g * 32768;          // per group: buf0 {A,B} | buf1 {A,B}
    const ushort* Ap = A + (size_t)m0 * 2048 + (size_t)g * 1024;
    const ushort* Bp = BT + (size_t)c0 * 2048 + (size_t)g * 1024;

    f32x4 z = {0.f, 0.f, 0.f, 0.f};
    f32x4 acc[2][2];
    acc[0][0] = z; acc[0][1] = z; acc[1][0] = z; acc[1][1] = z;

    stage64x64(Ap, 2048, base, t256);
    stage64x64(Bp, 2048, base + 8192, t256);
    for (int ts = 0; ts < 16; ++ts) {
        char* cur = base + (ts & 1) * 16384;
        if (ts < 15) {
            char* nxt = base + ((ts + 1) & 1) * 16384;
            stage64x64(Ap + (ts + 1) * 64, 2048, nxt, t256);
            stage64x64(Bp + (ts + 1) * 64, 2048, nxt + 8192, t256);
            vmwait4();                    // my 4 loads for cur are done
        } else {
            vmwait0();
        }
        blockbar();                       // everyone's cur loads done
#pragma unroll
        for (int s = 0; s < 2; ++s) {
            const int kb = s * 64 + l4 * 16;
            bf16x8 aF[2], bF[2];
#pragma unroll
            for (int f = 0; f < 2; ++f) {
                aF[f] = fragld(cur, wr * 32 + f * 16 + l15, kb);
                bF[f] = fragld(cur + 8192, wc * 32 + f * 16 + l15, kb);
            }
#pragma unroll
            for (int i = 0; i < 2; ++i)
#pragma unroll
                for (int j = 0; j < 2; ++j)
                    acc[i][j] = __builtin_amdgcn_mfma_f32_16x16x32_bf16(aF[i], bF[j], acc[i][j], 0, 0, 0);
        }
        lgwait0();                        // my ds_reads of cur done
        blockbar();                       // everyone done reading cur -> reusable
    }

    // cross-group reduce + epilogue (post-pipeline; plain syncthreads fine)
    float* red = (float*)ls;              // 64*65*4 = 16640 B
    ushort* tileo = (ushort*)(ls + 17408);
    if (g == 0) {
#pragma unroll
        for (int i = 0; i < 2; ++i)
#pragma unroll
            for (int j = 0; j < 2; ++j) {
                const int lrb = wr * 32 + i * 16 + l4 * 4;
                const int lc = wc * 32 + j * 16 + l15;
#pragma unroll
                for (int r = 0; r < 4; ++r) red[(lrb + r) * 65 + lc] = acc[i][j][r];
            }
    }
    __syncthreads();
    if (g == 1) {
#pragma unroll
        for (int i = 0; i < 2; ++i)
#pragma unroll
            for (int j = 0; j < 2; ++j) {
                const int lrb = wr * 32 + i * 16 + l4 * 4;
                const int lc = wc * 32 + j * 16 + l15;
                float vv[4];
#pragma unroll
                for (int r = 0; r < 4; ++r) vv[r] = red[(lrb + r) * 65 + lc] + acc[i][j][r];
                if (MODE == 1) {
                    ushort4 ci = *(const ushort4*)&CinT[(size_t)(c0 + lc) * 2048 + m0 + lrb];
                    vv[0] = 2.f * vv[0] - bf16_to_f32(ci.x);
                    vv[1] = 2.f * vv[1] - bf16_to_f32(ci.y);
                    vv[2] = 2.f * vv[2] - bf16_to_f32(ci.z);
                    vv[3] = 2.f * vv[3] - bf16_to_f32(ci.w);
                }
                ushort4 p;
                p.x = f32_to_bf16(vv[0]); p.y = f32_to_bf16(vv[1]);
                p.z = f32_to_bf16(vv[2]); p.w = f32_to_bf16(vv[3]);
                *(ushort4*)&YT[(size_t)(c0 + lc) * 2048 + m0 + lrb] = p;
                tileo[(lrb + 0) * 64 + lc] = p.x;
                tileo[(lrb + 1) * 64 + lc] = p.y;
                tileo[(lrb + 2) * 64 + lc] = p.z;
                tileo[(lrb + 3) * 64 + lc] = p.w;
            }
    }
    __syncthreads();
    {
        int row = t >> 3, ch = t & 7;
        *(uint4*)&Yo[(size_t)(m0 + row) * 512 + c0 + ch * 8] = *(uint4*)&tileo[row * 64 + ch * 8];
    }
}

// =================== gemm3 body: WaX 2-product (Wa1@X1 + Wa1@X2), in-block K-split ===================
__device__ __forceinline__ void gemm3_body(int bx, const ushort* __restrict__ A1,
        const ushort* __restrict__ B1, const ushort* __restrict__ B2,
        float* __restrict__ WaXT, char* ls) {
    const int t = threadIdx.x;
    const int g = t >> 8, t256 = t & 255;
    const int m0 = (bx & 31) * 64, c0 = (bx >> 5) * 64;
    const int lane = t & 63;
    const int wg = (t >> 6) & 3, wr = wg >> 1, wc = wg & 1;
    const int l15 = lane & 15, l4 = lane >> 4;
    char* base = ls + g * 24576;          // per group: A1, B1, B2 x 8KB
    const size_t kbase = (size_t)g * 1024;

    f32x4 z = {0.f, 0.f, 0.f, 0.f};
    f32x4 acc[2][2];
    acc[0][0] = z; acc[0][1] = z; acc[1][0] = z; acc[1][1] = z;

    for (int k0 = 0; k0 < 1024; k0 += 64) {
        stage64x64(A1 + (size_t)m0 * 2048 + kbase + k0, 2048, base + 0 * 8192, t256);
        stage64x64(B1 + (size_t)c0 * 2048 + kbase + k0, 2048, base + 1 * 8192, t256);
        stage64x64(B2 + (size_t)c0 * 2048 + kbase + k0, 2048, base + 2 * 8192, t256);
        __syncthreads();
#pragma unroll
        for (int s = 0; s < 2; ++s) {
            const int kb = s * 64 + l4 * 16;
            bf16x8 a1F[2], b1F[2], b2F[2];
#pragma unroll
            for (int f = 0; f < 2; ++f) {
                const int ar = wr * 32 + f * 16 + l15;
                const int br = wc * 32 + f * 16 + l15;
                a1F[f] = fragld(base + 0 * 8192, ar, kb);
                b1F[f] = fragld(base + 1 * 8192, br, kb);
                b2F[f] = fragld(base + 2 * 8192, br, kb);
            }
#pragma unroll
            for (int i = 0; i < 2; ++i)
#pragma unroll
                for (int j = 0; j < 2; ++j) {
                    f32x4 a = acc[i][j];
                    a = __builtin_amdgcn_mfma_f32_16x16x32_bf16(a1F[i], b1F[j], a, 0, 0, 0);
                    a = __builtin_amdgcn_mfma_f32_16x16x32_bf16(a1F[i], b2F[j], a, 0, 0, 0);
                    acc[i][j] = a;
                }
        }
        __syncthreads();
    }

    float* red = (float*)ls;
    if (g == 0) {
#pragma unroll
        for (int i = 0; i < 2; ++i)
#pragma unroll
            for (int j = 0; j < 2; ++j) {
                const int lrb = wr * 32 + i * 16 + l4 * 4;
                const int lc = wc * 32 + j * 16 + l15;
#pragma unroll
                for (int r = 0; r < 4; ++r) red[(lrb + r) * 65 + lc] = acc[i][j][r];
            }
    }
    __syncthreads();
    if (g == 1) {
#pragma unroll
        for (int i = 0; i < 2; ++i)
#pragma unroll
            for (int j = 0; j < 2; ++j) {
                const int lrb = wr * 32 + i * 16 + l4 * 4;
                const int lc = wc * 32 + j * 16 + l15;
                f32x4 v;
#pragma unroll
                for (int r = 0; r < 4; ++r) v[r] = red[(lrb + r) * 65 + lc] + acc[i][j][r];
                *(f32x4*)&WaXT[(size_t)(c0 + lc) * 2048 + m0 + lrb] = v;
            }
    }
}

// =================== gram body: 256 blocks (8 b x 32 chunks of 64 n), 512 thr ===================
__device__ __forceinline__ void gram_body(int bx, const float* __restrict__ WaXT,
        const ushort* __restrict__ XT1, const ushort* __restrict__ XT2,
        float* __restrict__ Gpart, char* lsraw) {
    const int b = bx & 7, chunk = bx >> 3;
    float (*Lw)[68] = (float(*)[68])lsraw;
    float (*Rx)[68] = (float(*)[68])(lsraw + 64 * 68 * 4);
    const int t = threadIdx.x;
    const int n0 = chunk * 64;
    {   // all 512 threads load 64x64 of Lw and Rx (8 f32 each)
        const int r = t >> 3, q = (t & 7) * 8;
        size_t a = (size_t)(b * 64 + r) * 2048 + n0 + q;
        *(float4*)&Lw[r][q]     = *(const float4*)&WaXT[a];
        *(float4*)&Lw[r][q + 4] = *(const float4*)&WaXT[a + 4];
#pragma unroll
        for (int h = 0; h < 2; ++h) {
            ushort4 h1 = *(const ushort4*)&XT1[a + h * 4];
            ushort4 h2 = *(const ushort4*)&XT2[a + h * 4];
            Rx[r][q + h * 4 + 0] = bf16_to_f32(h1.x) + bf16_to_f32(h2.x);
            Rx[r][q + h * 4 + 1] = bf16_to_f32(h1.y) + bf16_to_f32(h2.y);
            Rx[r][q + h * 4 + 2] = bf16_to_f32(h1.z) + bf16_to_f32(h2.z);
            Rx[r][q + h * 4 + 3] = bf16_to_f32(h1.w) + bf16_to_f32(h2.w);
        }
    }
    __syncthreads();
    if (t < 256) {
        const int tx = t & 15, ty = t >> 4;
        float acc[4][4] = {{0.f,0.f,0.f,0.f},{0.f,0.f,0.f,0.f},{0.f,0.f,0.f,0.f},{0.f,0.f,0.f,0.f}};
        for (int n = 0; n < 64; ++n) {
            float a[4], bb[4];
#pragma unroll
            for (int i = 0; i < 4; ++i) { a[i] = Lw[ty * 4 + i][n]; bb[i] = Rx[tx * 4 + i][n]; }
#pragma unroll
            for (int i = 0; i < 4; ++i)
#pragma unroll
                for (int j = 0; j < 4; ++j) acc[i][j] = fmaf(a[i], bb[j], acc[i][j]);
        }
        float* gp = Gpart + (size_t)(chunk * 8 + b) * 4096;
#pragma unroll
        for (int i = 0; i < 4; ++i)
            *(float4*)&gp[(ty * 4 + i) * 64 + tx * 4] =
                make_float4(acc[i][0], acc[i][1], acc[i][2], acc[i][3]);
    }
}

// =================== cheb body: per-batch 64x64 Chebyshev; 512 thr, t<256 compute ===================
__device__ __forceinline__ void cheb_body(int b, const float* __restrict__ Gpart,
        const float* __restrict__ Thd, ushort* __restrict__ DT1, ushort* __restrict__ DT2,
        char* lsraw) {
    float (*Gs)[68]  = (float(*)[68])lsraw;
    float (*C2s)[68] = (float(*)[68])(lsraw + 17408);
    float (*C3s)[68] = (float(*)[68])(lsraw + 34816);
    const int t = threadIdx.x;
    for (int i = t; i < 4096; i += 512) {      // fold 32-chunk reduce in
        float s = 0.f;
#pragma unroll
        for (int c = 0; c < 32; ++c) s += Gpart[((size_t)c * 8 + b) * 4096 + i];
        Gs[i >> 6][i & 63] = s;
    }
    __syncthreads();
    const int tx = t & 15, ty = (t >> 4) & 15;
    const int r0 = ty * 4, c0 = tx * 4;
    const bool act = t < 256;

    if (act) {   // C2 = 2*G@G - I
        float p[4][4] = {{0,0,0,0},{0,0,0,0},{0,0,0,0},{0,0,0,0}};
        for (int k = 0; k < 64; ++k) {
            float ar[4] = {Gs[r0][k], Gs[r0+1][k], Gs[r0+2][k], Gs[r0+3][k]};
            float4 bv = *(const float4*)&Gs[k][c0];
            float br[4] = {bv.x, bv.y, bv.z, bv.w};
#pragma unroll
            for (int i = 0; i < 4; ++i)
#pragma unroll
                for (int j = 0; j < 4; ++j) p[i][j] = fmaf(ar[i], br[j], p[i][j]);
        }
#pragma unroll
        for (int i = 0; i < 4; ++i)
#pragma unroll
            for (int j = 0; j < 4; ++j)
                C2s[r0+i][c0+j] = 2.f * p[i][j] - ((r0+i) == (c0+j) ? 1.f : 0.f);
    }
    __syncthreads();
    if (act) {   // C3 = 2*G@C2 - G
        float q[4][4] = {{0,0,0,0},{0,0,0,0},{0,0,0,0},{0,0,0,0}};
        for (int k = 0; k < 64; ++k) {
            float ar[4] = {Gs[r0][k], Gs[r0+1][k], Gs[r0+2][k], Gs[r0+3][k]};
            float4 bv = *(const float4*)&C2s[k][c0];
            float br[4] = {bv.x, bv.y, bv.z, bv.w};
#pragma unroll
            for (int i = 0; i < 4; ++i)
#pragma unroll
                for (int j = 0; j < 4; ++j) q[i][j] = fmaf(ar[i], br[j], q[i][j]);
        }
#pragma unroll
        for (int i = 0; i < 4; ++i)
#pragma unroll
            for (int j = 0; j < 4; ++j)
                C3s[r0+i][c0+j] = 2.f * q[i][j] - Gs[r0+i][c0+j];
    }
    __syncthreads();
    float d[4][4];
    if (act) {   // D = Thd0 + G@Thd1 + C2@Thd2 + C3@Thd3
#pragma unroll
        for (int i = 0; i < 4; ++i) {
            float4 t0 = *(const float4*)&Thd[(r0+i) * 64 + c0];
            d[i][0] = t0.x; d[i][1] = t0.y; d[i][2] = t0.z; d[i][3] = t0.w;
        }
        for (int k = 0; k < 64; ++k) {
            float4 t1 = *(const float4*)&Thd[4096 + k * 64 + c0];
            float4 t2 = *(const float4*)&Thd[8192 + k * 64 + c0];
            float4 t3 = *(const float4*)&Thd[12288 + k * 64 + c0];
            float a1[4] = {Gs[r0][k], Gs[r0+1][k], Gs[r0+2][k], Gs[r0+3][k]};
            float a2[4] = {C2s[r0][k], C2s[r0+1][k], C2s[r0+2][k], C2s[r0+3][k]};
            float a3[4] = {C3s[r0][k], C3s[r0+1][k], C3s[r0+2][k], C3s[r0+3][k]};
            float b1[4] = {t1.x, t1.y, t1.z, t1.w};
            float b2[4] = {t2.x, t2.y, t2.z, t2.w};
            float b3[4] = {t3.x, t3.y, t3.z, t3.w};
#pragma unroll
            for (int i = 0; i < 4; ++i)
#pragma unroll
                for (int j = 0; j < 4; ++j) {
                    d[i][j] = fmaf(a1[i], b1[j], d[i][j]);
                    d[i][j] = fmaf(a2[i], b2[j], d[i][j]);
                    d[i][j] = fmaf(a3[i], b3[j], d[i][j]);
                }
        }
    }
    __syncthreads();
    if (act) {
#pragma unroll
        for (int i = 0; i < 4; ++i)
#pragma unroll
            for (int j = 0; j < 4; ++j) Gs[r0 + i][c0 + j] = d[i][j];
    }
    __syncthreads();
    for (int it = 0; it < 8; ++it) {
        int idx = it * 512 + t;              // o*64 + i (transposed emit)
        int o = idx >> 6, ii = idx & 63;
        ushort h1, h2;
        split2(Gs[ii][o], h1, h2);
        DT1[b * 4096 + idx] = h1;
        DT2[b * 4096 + idx] = h2;
    }
}

// =================== mega kernels: block-role fusion for co-residency ===================
__global__ __launch_bounds__(512, 4) void mega1(const ushort* __restrict__ Wa1,
        const ushort* __restrict__ XT1, const ushort* __restrict__ XT2,
        float* __restrict__ WaXT,
        const ushort* __restrict__ Ws16, ushort* __restrict__ Y1T, ushort* __restrict__ Y1o) {
    __shared__ __align__(16) char ls[65536];
    const int bx = blockIdx.x;
    if (bx < 256) gemm3_body(bx, Wa1, XT1, XT2, WaXT, ls);
    else          gemm_s_body<0>(bx - 256, Ws16, XT1, nullptr, Y1T, Y1o, ls);
}

__global__ __launch_bounds__(512, 4) void mega2(const ushort* __restrict__ Ws16,
        const ushort* __restrict__ Y1T, const ushort* __restrict__ XT1,
        ushort* __restrict__ Y2T, ushort* __restrict__ Y2o,
        const float* __restrict__ WaXT, const ushort* __restrict__ XT2,
        float* __restrict__ Gpart) {
    __shared__ __align__(16) char ls[65536];
    const int bx = blockIdx.x;
    if (bx < 256) gemm_s_body<1>(bx, Ws16, Y1T, XT1, Y2T, Y2o, ls);
    else          gram_body(bx - 256, WaXT, XT1, XT2, Gpart, ls);
}

__global__ __launch_bounds__(512, 4) void mega3(const ushort* __restrict__ Ws16,
        const ushort* __restrict__ Y2T, const ushort* __restrict__ Y1T,
        ushort* __restrict__ Y3T, ushort* __restrict__ Y3o,
        const float* __restrict__ Gpart, const float* __restrict__ Thd,
        ushort* __restrict__ DT1, ushort* __restrict__ DT2) {
    __shared__ __align__(16) char ls[65536];
    const int bx = blockIdx.x;
    if (bx < 256) gemm_s_body<1>(bx, Ws16, Y2T, Y1T, Y3T, Y3o, ls);
    else          cheb_body(bx - 256, Gpart, Thd, DT1, DT2, ls);
}

// =================== fused epilogue (R4-proven) ===================
__global__ __launch_bounds__(256) void ep_fused(const ushort* __restrict__ ThsT,
                                                const ushort* __restrict__ DT1, const ushort* __restrict__ DT2,
                                                const ushort* __restrict__ X1o, const ushort* __restrict__ X2o,
                                                const ushort* __restrict__ Y1o, const ushort* __restrict__ Y2o,
                                                const ushort* __restrict__ Y3o,
                                                float* __restrict__ out) {
    __shared__ __align__(16) char ls[65536];
    const int b = blockIdx.y, n0 = blockIdx.x * 64;
    const int t = threadIdx.x, lane = t & 63, w = t >> 6, wr = w >> 1, wc = w & 1;
    const int l15 = lane & 15, l4 = lane >> 4;
    stage64x64(X1o + (size_t)n0 * 512 + b * 64, 512, ls + 0 * 8192, t);
    stage64x64(Y1o + (size_t)n0 * 512 + b * 64, 512, ls + 1 * 8192, t);
    stage64x64(Y2o + (size_t)n0 * 512 + b * 64, 512, ls + 2 * 8192, t);
    stage64x64(Y3o + (size_t)n0 * 512 + b * 64, 512, ls + 3 * 8192, t);
    stage64x64(ThsT + 0 * 4096, 64, ls + 4 * 8192, t);
    stage64x64(ThsT + 1 * 4096, 64, ls + 5 * 8192, t);
    stage64x64(ThsT + 2 * 4096, 64, ls + 6 * 8192, t);
    stage64x64(ThsT + 3 * 4096, 64, ls + 7 * 8192, t);
    __syncthreads();
    f32x4 z = {0.f, 0.f, 0.f, 0.f};
    f32x4 as[2][2], ad[2][2];
    as[0][0] = z; as[0][1] = z; as[1][0] = z; as[1][1] = z;
    ad[0][0] = z; ad[0][1] = z; ad[1][0] = z; ad[1][1] = z;
#pragma unroll
    for (int s = 0; s < 2; ++s) {
        const int kb = s * 64 + l4 * 16;
#pragma unroll
        for (int p = 0; p < 4; ++p) {
            bf16x8 aF[2], bF[2];
#pragma unroll
            for (int f = 0; f < 2; ++f) {
                aF[f] = fragld(ls + (4 + p) * 8192, wr * 32 + f * 16 + l15, kb);
                bF[f] = fragld(ls + p * 8192, wc * 32 + f * 16 + l15, kb);
            }
#pragma unroll
            for (int i = 0; i < 2; ++i)
#pragma unroll
                for (int j = 0; j < 2; ++j)
                    as[i][j] = __builtin_amdgcn_mfma_f32_16x16x32_bf16(aF[i], bF[j], as[i][j], 0, 0, 0);
        }
    }
    __syncthreads();
    stage64x64(DT1 + b * 4096, 64, ls + 1 * 8192, t);
    stage64x64(DT2 + b * 4096, 64, ls + 2 * 8192, t);
    stage64x64(X2o + (size_t)n0 * 512 + b * 64, 512, ls + 3 * 8192, t);
    __syncthreads();
#pragma unroll
    for (int s = 0; s < 2; ++s) {
        const int kb = s * 64 + l4 * 16;
        bf16x8 a1[2], a2[2], b0[2], b3[2];
#pragma unroll
        for (int f = 0; f < 2; ++f) {
            a1[f] = fragld(ls + 1 * 8192, wr * 32 + f * 16 + l15, kb);
            a2[f] = fragld(ls + 2 * 8192, wr * 32 + f * 16 + l15, kb);
            b0[f] = fragld(ls + 0 * 8192, wc * 32 + f * 16 + l15, kb);
            b3[f] = fragld(ls + 3 * 8192, wc * 32 + f * 16 + l15, kb);
        }
#pragma unroll
        for (int i = 0; i < 2; ++i)
#pragma unroll
            for (int j = 0; j < 2; ++j) {
                f32x4 a = ad[i][j];
                a = __builtin_amdgcn_mfma_f32_16x16x32_bf16(a1[i], b0[j], a, 0, 0, 0);
                a = __builtin_amdgcn_mfma_f32_16x16x32_bf16(a1[i], b3[j], a, 0, 0, 0);
                a = __builtin_amdgcn_mfma_f32_16x16x32_bf16(a2[i], b0[j], a, 0, 0, 0);
                ad[i][j] = a;
            }
    }
#pragma unroll
    for (int i = 0; i < 2; ++i)
#pragma unroll
        for (int j = 0; j < 2; ++j) {
            const int ob = wr * 32 + i * 16 + l4 * 4;
            const int nn = wc * 32 + j * 16 + l15;
            float4 o4;
            o4.x = fmaxf(as[i][j][0], 0.f) + fmaxf(ad[i][j][0], 0.f);
            o4.y = fmaxf(as[i][j][1], 0.f) + fmaxf(ad[i][j][1], 0.f);
            o4.z = fmaxf(as[i][j][2], 0.f) + fmaxf(ad[i][j][2], 0.f);
            o4.w = fmaxf(as[i][j][3], 0.f) + fmaxf(ad[i][j][3], 0.f);
            *(float4*)&out[((size_t)b * 2048 + n0 + nn) * 64 + ob] = o4;
        }
}

extern "C" void kernel_launch(void* const* d_in, const int* in_sizes, int n_in,
                              void* d_out, int out_size, void* d_ws, size_t ws_size,
                              hipStream_t stream) {
    (void)in_sizes; (void)n_in; (void)out_size;
    const float* X   = (const float*)d_in[0];
    const float* Ws  = (const float*)d_in[1];
    const float* Wa  = (const float*)d_in[2];
    const float* Ths = (const float*)d_in[3];
    const float* Thd = (const float*)d_in[4];

    char* p = (char*)d_ws;
    auto alloc = [&](size_t bytes) { char* r = p; p += (bytes + 255) & ~(size_t)255; return r; };
    ushort* XT1 = (ushort*)alloc(512ull * 2048 * 2);
    ushort* XT2 = (ushort*)alloc(512ull * 2048 * 2);
    ushort* X1o = (ushort*)alloc(2048ull * 512 * 2);
    ushort* X2o = (ushort*)alloc(2048ull * 512 * 2);
    ushort* Ws16 = (ushort*)alloc(2048ull * 2048 * 2);
    ushort* Wa1 = (ushort*)alloc(2048ull * 2048 * 2);
    ushort* Y1T = (ushort*)alloc(512ull * 2048 * 2);
    ushort* Y2T = (ushort*)alloc(512ull * 2048 * 2);
    ushort* Y3T = (ushort*)alloc(512ull * 2048 * 2);
    ushort* Y1o = (ushort*)alloc(2048ull * 512 * 2);
    ushort* Y2o = (ushort*)alloc(2048ull * 512 * 2);
    ushort* Y3o = (ushort*)alloc(2048ull * 512 * 2);
    float*  Gpart = (float*)alloc(32ull * 8 * 4096 * 4);
    ushort* DT1 = (ushort*)alloc(8ull * 4096 * 2);
    ushort* DT2 = (ushort*)alloc(8ull * 4096 * 2);
    ushort* ThsT = (ushort*)alloc(4ull * 4096 * 2);
    if ((size_t)(p - (char*)d_ws) > ws_size) return;   // visible failure if ws too small
    float* WaXT = (float*)d_out;                       // 4MB scratch, overwritten by ep_fused later

    prep_all<<<4416, 256, 0, stream>>>(X, XT1, XT2, X1o, X2o, Ws, Ws16, Wa, Wa1, Ths, ThsT);
    mega1<<<512, 512, 0, stream>>>(Wa1, XT1, XT2, WaXT, Ws16, Y1T, Y1o);
    mega2<<<512, 512, 0, stream>>>(Ws16, Y1T, XT1, Y2T, Y2o, WaXT, XT2, Gpart);
    mega3<<<264, 512, 0, stream>>>(Ws16, Y2T, Y1T, Y3T, Y3o, Gpart, Thd, DT1, DT2);
    ep_fused<<<dim3(32, 8), 256, 0, stream>>>(ThsT, DT1, DT2, X1o, X2o, Y1o, Y2o, Y3o, (float*)d_out);
}